// Round 9
// baseline (644.267 us; speedup 1.0000x reference)
//
#include <hip/hip_runtime.h>

typedef unsigned short u16;
typedef unsigned int   u32;
typedef __attribute__((ext_vector_type(8))) short short8;   // 8 x bf16 (4 VGPRs)
typedef __attribute__((ext_vector_type(4))) float f32x4;    // MFMA accum

// ---------------- helpers ----------------
__device__ __forceinline__ u16 f2bf(float f) {
  union { float f; u32 u; } v; v.f = f;
  u32 r = v.u + 0x7fffu + ((v.u >> 16) & 1u);   // RNE
  return (u16)(r >> 16);
}
__device__ __forceinline__ float bf2f(u32 bits) {
  union { u32 u; float f; } v; v.u = bits << 16; return v.f;
}
// async global->LDS, 16B per lane. LDS dest is WAVE-UNIFORM base; HW adds lane*16.
__device__ __forceinline__ void gl_lds16(const u16* g, u16* l) {
  __builtin_amdgcn_global_load_lds(
      (const __attribute__((address_space(1))) void*)g,
      (__attribute__((address_space(3))) void*)l, 16, 0, 0);
}

// ---------------- problem constants ----------------
static constexpr int DIM  = 2048;
static constexpr int NQKV = 6144;

// ---------------- f32 -> bf16 convert (4 elems/thread) ----------------
__global__ __launch_bounds__(256) void conv_f32_bf16(const float* __restrict__ in,
                                                     u16* __restrict__ out, int n4) {
  int id = blockIdx.x * 256 + threadIdx.x;
  if (id >= n4) return;
  float4 v = ((const float4*)in)[id];
  u32 lo = (u32)f2bf(v.x) | ((u32)f2bf(v.y) << 16);
  u32 hi = (u32)f2bf(v.z) | ((u32)f2bf(v.w) << 16);
  ((uint2*)out)[id] = make_uint2(lo, hi);
}

// ---------------- transpose + convert: W[K][N] f32 -> Wt[N][K] bf16 ----------------
__global__ void tconv_kernel(const float* __restrict__ W, u16* __restrict__ Wt, int K, int N) {
  __shared__ float t[32][33];
  int tx = threadIdx.x, ty = threadIdx.y;           // 32 x 8
  int n0 = blockIdx.x * 32, k0 = blockIdx.y * 32;
  #pragma unroll
  for (int i = 0; i < 4; ++i)
    t[ty + i*8][tx] = W[(size_t)(k0 + ty + i*8) * N + n0 + tx];
  __syncthreads();
  #pragma unroll
  for (int i = 0; i < 4; ++i)
    Wt[(size_t)(n0 + ty + i*8) * K + k0 + tx] = f2bf(t[tx][ty + i*8]);
}

// ---------------- RMSNorm in-place on bf16 rows of 128 (1 wave / row) ----------------
__global__ __launch_bounds__(256) void rms_kernel(u16* __restrict__ x,
                                                  const float* __restrict__ g, int nrows) {
  int w = threadIdx.x >> 6, lane = threadIdx.x & 63;
  int rid = blockIdx.x * 4 + w;
  if (rid >= nrows) return;
  u32* row = (u32*)x + (size_t)rid * 64;
  u32 u = row[lane];
  float f0 = bf2f(u & 0xffffu), f1 = bf2f(u >> 16);
  float s = f0*f0 + f1*f1;
  #pragma unroll
  for (int off = 1; off <= 32; off <<= 1) s += __shfl_xor(s, off);
  float r = rsqrtf(s * (1.0f/128.0f) + 1e-6f);
  float g0 = g[lane*2], g1 = g[lane*2+1];
  row[lane] = (u32)f2bf(f0*r*g0) | ((u32)f2bf(f1*r*g1) << 16);
}

// ---------------- V transpose: [nh][256 key][128 d] -> [nh][128 d][256 key] ----------
__global__ __launch_bounds__(256)
void vtrans_kernel(const u16* __restrict__ src, u16* __restrict__ dst) {
  __shared__ u16 t[64][130];
  int nh = blockIdx.x, k0 = blockIdx.y * 64;
  const u16* s = src + ((size_t)nh*256 + k0)*128;
  u16* d = dst + (size_t)nh*128*256 + k0;
  int tid = threadIdx.x;
  #pragma unroll
  for (int it = 0; it < 4; ++it) {
    int c = tid + it*256;
    int row = c >> 4, ch = c & 15;          // row 0..63, 16B chunk 0..15
    short8 v = *(const short8*)(s + row*128 + ch*8);
    u32* dst32 = (u32*)&t[row][ch*8];
    const u32* v32 = (const u32*)&v;
    dst32[0] = v32[0]; dst32[1] = v32[1]; dst32[2] = v32[2]; dst32[3] = v32[3];
  }
  __syncthreads();
  #pragma unroll
  for (int it = 0; it < 4; ++it) {
    int c = tid + it*256;
    int dr = c >> 3, kg = c & 7;            // d-row 0..127, key-group 0..7
    short8 v;
    #pragma unroll
    for (int j = 0; j < 8; ++j) v[j] = (short)t[kg*8+j][dr];
    *(short8*)(d + (size_t)dr*256 + kg*8) = v;
  }
}

// ============== 256x256-tile pipelined GEMM, BK=32, 4-buffer ring, 8 waves ==========
// (R6 known-good form: top-of-tile counted vmcnt + single barrier, 0 bank conflicts)
template<int EPI>
__global__ __launch_bounds__(512, 2)
void gemm256(const u16* __restrict__ A, const u16* __restrict__ Bt,
             const float* __restrict__ bias,
             u16* __restrict__ o0, u16* __restrict__ o1, u16* __restrict__ o2,
             float* __restrict__ of, int ldo, int M, int N, int K)
{
  __shared__ __align__(16) u16 As[4][256*32];
  __shared__ __align__(16) u16 Bs[4][256*32];
  const int NT = K >> 5;
  int tid = threadIdx.x, lane = tid & 63, w = tid >> 6;
  int l15 = lane & 15, l4 = lane >> 4;
  int wm = w >> 2, wn = w & 3;                   // 2M x 4N wave grid

  int nbx = gridDim.x;
  int nwg = nbx * gridDim.y;
  int bid = blockIdx.y * nbx + blockIdx.x;
  int cpx = nwg >> 3;
  int swz = (bid & 7) * cpx + (bid >> 3);
  int n0 = (swz % nbx) * 256, m0 = (swz / nbx) * 256;

  int srow = tid >> 2, skc = (tid & 3) ^ ((tid >> 3) & 3);
  const u16* aS = A  + (size_t)(m0 + srow) * K + skc * 8;
  const u16* bS = Bt + (size_t)(n0 + srow) * K + skc * 8;
  const size_t halfStride = 128 * (size_t)K;
  const int ldsBase = w * 512;

  #define STAGE_A(slot, tt, half) \
    gl_lds16(aS + (size_t)(tt)*32 + (half)*halfStride, &As[slot][(half)*4096 + ldsBase])
  #define STAGE_B(slot, tt, half) \
    gl_lds16(bS + (size_t)(tt)*32 + (half)*halfStride, &Bs[slot][(half)*4096 + ldsBase])

  #pragma unroll
  for (int pt = 0; pt < 3; ++pt) {
    STAGE_A(pt, pt, 0); STAGE_A(pt, pt, 1);
    STAGE_B(pt, pt, 0); STAGE_B(pt, pt, 1);
  }

  f32x4 acc[8][4] = {};

  for (int t = 0; t < NT; ++t) {
    if (t < NT - 2)       asm volatile("s_waitcnt vmcnt(8)" ::: "memory");
    else if (t == NT - 2) asm volatile("s_waitcnt vmcnt(4)" ::: "memory");
    else                  asm volatile("s_waitcnt vmcnt(0)" ::: "memory");
    __builtin_amdgcn_s_barrier();
    asm volatile("" ::: "memory");

    const u16* ab = As[t & 3];
    const u16* bb = Bs[t & 3];
    bool st = (t + 3 < NT);
    int slot = (t + 3) & 3;

    short8 bf_[4];
    #pragma unroll
    for (int j = 0; j < 4; ++j) {
      int rb = wn*64 + j*16 + l15;
      bf_[j] = *(const short8*)((const char*)bb + rb*64 + ((l4 ^ ((rb>>1)&3))*16));
    }

    short8 af[4];
    #pragma unroll
    for (int i = 0; i < 4; ++i) {
      int ra = wm*128 + i*16 + l15;
      af[i] = *(const short8*)((const char*)ab + ra*64 + ((l4 ^ ((ra>>1)&3))*16));
    }
    if (st) { STAGE_A(slot, t+3, 0); STAGE_A(slot, t+3, 1); }
    __builtin_amdgcn_s_setprio(1);
    #pragma unroll
    for (int i = 0; i < 4; ++i)
      #pragma unroll
      for (int j = 0; j < 4; ++j)
        acc[i][j] = __builtin_amdgcn_mfma_f32_16x16x32_bf16(af[i], bf_[j], acc[i][j], 0, 0, 0);
    __builtin_amdgcn_s_setprio(0);

    #pragma unroll
    for (int i = 0; i < 4; ++i) {
      int ra = wm*128 + 64 + i*16 + l15;
      af[i] = *(const short8*)((const char*)ab + ra*64 + ((l4 ^ ((ra>>1)&3))*16));
    }
    if (st) { STAGE_B(slot, t+3, 0); STAGE_B(slot, t+3, 1); }
    __builtin_amdgcn_s_setprio(1);
    #pragma unroll
    for (int i = 0; i < 4; ++i)
      #pragma unroll
      for (int j = 0; j < 4; ++j)
        acc[4+i][j] = __builtin_amdgcn_mfma_f32_16x16x32_bf16(af[i], bf_[j], acc[4+i][j], 0, 0, 0);
    __builtin_amdgcn_s_setprio(0);
  }
  #undef STAGE_A
  #undef STAGE_B

  #pragma unroll
  for (int i = 0; i < 8; ++i)
    #pragma unroll
    for (int j = 0; j < 4; ++j)
      #pragma unroll
      for (int r = 0; r < 4; ++r) {
        int m = m0 + wm*128 + i*16 + l4*4 + r;
        int n = n0 + wn*64  + j*16 + l15;
        float v = acc[i][j][r] + bias[n];
        if (EPI == 0) {           // vid QKV -> windowed [win][head][p][128]
          int which = n >> 11, head = (n >> 7) & 15, d = n & 127;
          int t = m >> 10, hh = (m >> 5) & 31, ww = m & 31;
          int win = ((t>>2)<<4) + ((hh>>3)<<2) + (ww>>3);
          int p   = ((t&3)<<6) + ((hh&7)<<3) + (ww&7);
          u16* dst = which == 0 ? o0 : (which == 1 ? o1 : o2);
          dst[((size_t)(win*16 + head)*256 + p)*128 + d] = f2bf(v);
        } else {                  // plain f32
          of[(size_t)m * ldo + n] = v;
        }
      }
}

// ---------------- 128x128-tile bf16 MFMA GEMM (small txt matrices) ----------------
template<int EPI>
__global__ __launch_bounds__(256)
void gemm128(const u16* __restrict__ A, const u16* __restrict__ Bt,
             const float* __restrict__ bias,
             u16* __restrict__ o0, u16* __restrict__ o1, u16* __restrict__ o2,
             float* __restrict__ of, int ldo, int M, int N, int K)
{
  __shared__ __align__(16) u16 As[128*32];
  __shared__ __align__(16) u16 Bs[128*32];
  int tid = threadIdx.x, lane = tid & 63, w = tid >> 6;
  int l15 = lane & 15, l4 = lane >> 4;
  int m0 = blockIdx.y * 128, n0 = blockIdx.x * 128;
  int wr = (w >> 1) * 64, wc = (w & 1) * 64;
  f32x4 acc[4][4] = {};

  int o0b = (w    )*1024 + lane*16;
  int o1b = (w + 4)*1024 + lane*16;
  int r0 = o0b >> 6, c0 = ((o0b >> 4) & 3) ^ ((r0 >> 1) & 3);
  int r1 = o1b >> 6, c1 = ((o1b >> 4) & 3) ^ ((r1 >> 1) & 3);
  const u16* a0 = A  + (size_t)(m0 + r0)*K + c0*8;
  const u16* a1 = A  + (size_t)(m0 + r1)*K + c1*8;
  const u16* b0 = Bt + (size_t)(n0 + r0)*K + c0*8;
  const u16* b1 = Bt + (size_t)(n0 + r1)*K + c1*8;
  u16* dA0 = As + (w    )*512;
  u16* dA1 = As + (w + 4)*512;
  u16* dB0 = Bs + (w    )*512;
  u16* dB1 = Bs + (w + 4)*512;

  for (int k0 = 0; k0 < K; k0 += 32) {
    gl_lds16(a0 + k0, dA0);
    gl_lds16(a1 + k0, dA1);
    gl_lds16(b0 + k0, dB0);
    gl_lds16(b1 + k0, dB1);
    __syncthreads();
    short8 af[4], bfr[4];
    #pragma unroll
    for (int t = 0; t < 4; ++t) {
      int ra = wr + t*16 + l15;
      af[t]  = *(const short8*)((const char*)As + ra*64 + ((l4 ^ ((ra>>1)&3))*16));
      int rb = wc + t*16 + l15;
      bfr[t] = *(const short8*)((const char*)Bs + rb*64 + ((l4 ^ ((rb>>1)&3))*16));
    }
    #pragma unroll
    for (int i = 0; i < 4; ++i)
      #pragma unroll
      for (int j = 0; j < 4; ++j)
        acc[i][j] = __builtin_amdgcn_mfma_f32_16x16x32_bf16(af[i], bfr[j], acc[i][j], 0, 0, 0);
    __syncthreads();
  }

  #pragma unroll
  for (int i = 0; i < 4; ++i)
    #pragma unroll
    for (int j = 0; j < 4; ++j)
      #pragma unroll
      for (int r = 0; r < 4; ++r) {
        int m = m0 + wr + i*16 + l4*4 + r;
        int n = n0 + wc + j*16 + l15;
        float v = acc[i][j][r] + bias[n];
        if (EPI == 1) {           // txt QKV -> [head][p][128]
          int which = n >> 11, head = (n >> 7) & 15, d = n & 127;
          u16* dst = which == 0 ? o0 : (which == 1 ? o1 : o2);
          dst[((size_t)head*256 + m)*128 + d] = f2bf(v);
        } else {                  // plain f32
          of[(size_t)m * ldo + n] = v;
        }
      }
}

// ---------------- fused windowed attention v4: K/V double-buffer, P in dead K-buf ----
// 2048 blocks, XCD-chunked (4 q-quarters of each (win,head) consecutive per XCD).
// 8 waves x 16 q-rows. LDS = 64 KB (2 blocks/CU). Per chunk:
//   barrier A (free ^cur) -> issue c+1 prefetch -> vmcnt(4) counted -> barrier B0 ->
//   QK -> barrier B1 (Ks[cur] dead) -> P-write into Ks[cur] (XOR chunk^(q&7)) -> PV.
__global__ __launch_bounds__(512, 4)
void attn_kernel(const u16* __restrict__ vq, const u16* __restrict__ vk, const u16* __restrict__ vv,
                 const u16* __restrict__ tq, const u16* __restrict__ tk, const u16* __restrict__ tv,
                 const float* __restrict__ gq_v, const float* __restrict__ gq_t,
                 u16* __restrict__ vo, float* __restrict__ to_acc)
{
  __shared__ __align__(16) u16 Ks[2*64*128];    // [buf][key][d] swizzled; cur reused for P
  __shared__ __align__(16) u16 Vt[2*128*64];    // [buf][d][key] swizzled
  int tid = threadIdx.x, lane = tid & 63, w = tid >> 6;
  int l15 = lane & 15, l4 = lane >> 4;
  int bid = blockIdx.x;
  int logical = (bid & 7) * 256 + (bid >> 3);
  int nh_ = logical >> 2, qq = logical & 3;
  int h = nh_ & 15;
  int n = nh_ >> 4;
  int qt = qq * 128 + w * 16;

  // ---- Q load + fused RMSNorm ----
  const u16* Qb; const float* gq;
  if (qt < 256) { Qb = vq + ((size_t)nh_*256 + qt)*128; gq = gq_v; }
  else          { Qb = tq + ((size_t)h  *256 + (qt-256))*128; gq = gq_t; }
  short8 qf[4];
  float qv[4][8];
  float ss = 0.f;
  #pragma unroll
  for (int dt = 0; dt < 4; ++dt) {
    qf[dt] = *(const short8*)(Qb + l15*128 + l4*8 + dt*32);
    #pragma unroll
    for (int j = 0; j < 8; ++j) {
      float f = bf2f((u16)qf[dt][j]);
      qv[dt][j] = f; ss += f*f;
    }
  }
  ss += __shfl_xor(ss, 16); ss += __shfl_xor(ss, 32);
  float rr = rsqrtf(ss * (1.0f/128.0f) + 1e-6f);
  #pragma unroll
  for (int dt = 0; dt < 4; ++dt) {
    float4 g0 = *(const float4*)(gq + l4*8 + dt*32);
    float4 g1 = *(const float4*)(gq + l4*8 + dt*32 + 4);
    qf[dt][0] = (short)f2bf(qv[dt][0]*rr*g0.x); qf[dt][1] = (short)f2bf(qv[dt][1]*rr*g0.y);
    qf[dt][2] = (short)f2bf(qv[dt][2]*rr*g0.z); qf[dt][3] = (short)f2bf(qv[dt][3]*rr*g0.w);
    qf[dt][4] = (short)f2bf(qv[dt][4]*rr*g1.x); qf[dt][5] = (short)f2bf(qv[dt][5]*rr*g1.y);
    qf[dt][6] = (short)f2bf(qv[dt][6]*rr*g1.z); qf[dt][7] = (short)f2bf(qv[dt][7]*rr*g1.w);
  }

  // ---- staging geometry (global_load_lds: wave-uniform LDS dest, per-lane src) ----
  int oK0 = w*1024 + lane*16, oK1 = oK0 + 8192;
  int kr0 = oK0 >> 8, kc0 = ((oK0 >> 4) & 15) ^ (kr0 & 7);
  int kr1 = oK1 >> 8, kc1 = ((oK1 >> 4) & 15) ^ (kr1 & 7);
  int vd0 = oK0 >> 7, vc0 = ((oK0 >> 4) & 7) ^ (vd0 & 7);
  int vd1 = oK1 >> 7, vc1 = ((oK1 >> 4) & 7) ^ (vd1 & 7);

  f32x4 o_[8] = {};
  float m_run[4] = {-1e30f,-1e30f,-1e30f,-1e30f};
  float l_run[4] = {0.f,0.f,0.f,0.f};
  const float scale = 0.08838834764831845f;

  #define STAGE_CHUNK(cc, buf)                                                        \
    {                                                                                 \
      int kb = (cc) * 64;                                                             \
      const u16* Kc; const u16* Vb; int vkb;                                          \
      if (kb < 256) { Kc = vk + ((size_t)nh_*256 + kb)*128;                           \
                      Vb = vv + (size_t)nh_*128*256; vkb = kb; }                      \
      else          { Kc = tk + ((size_t)h*256 + (kb-256))*128;                       \
                      Vb = tv + (size_t)h*128*256; vkb = kb - 256; }                  \
      gl_lds16(Kc + kr0*128 + kc0*8, Ks + (buf)*8192 + w*512);                        \
      gl_lds16(Kc + kr1*128 + kc1*8, Ks + (buf)*8192 + w*512 + 4096);                 \
      gl_lds16(Vb + (size_t)vd0*256 + vkb + vc0*8, Vt + (buf)*8192 + w*512);          \
      gl_lds16(Vb + (size_t)vd1*256 + vkb + vc1*8, Vt + (buf)*8192 + w*512 + 4096);   \
    }

  // prologue: stage chunk 0
  STAGE_CHUNK(0, 0);

  for (int c = 0; c < 8; ++c) {
    int cur = c & 1;
    __builtin_amdgcn_s_barrier();          // A: prev chunk's readers of ^cur done
    if (c < 7) STAGE_CHUNK(c + 1, cur ^ 1);
    if (c < 7) asm volatile("s_waitcnt vmcnt(4)" ::: "memory");
    else       asm volatile("s_waitcnt vmcnt(0)" ::: "memory");
    __builtin_amdgcn_s_barrier();          // B0: all waves' chunk-c loads visible
    const char* KsB = (const char*)(Ks + cur*8192);
    const char* VtB = (const char*)(Vt + cur*8192);

    // ---- S = Q K^T ----
    f32x4 s4[4];
    __builtin_amdgcn_s_setprio(1);
    #pragma unroll
    for (int kt = 0; kt < 4; ++kt) {
      f32x4 sa = {0.f,0.f,0.f,0.f};
      int key = kt*16 + l15;
      #pragma unroll
      for (int dt = 0; dt < 4; ++dt) {
        int c16b = l4 + dt*4;
        short8 kf = *(const short8*)(KsB + key*256 + (((c16b ^ (key&7)))*16));
        sa = __builtin_amdgcn_mfma_f32_16x16x32_bf16(qf[dt], kf, sa, 0, 0, 0);
      }
      s4[kt] = sa;
    }
    __builtin_amdgcn_s_setprio(0);

    // ---- online softmax ----
    float f_[4];
    #pragma unroll
    for (int r = 0; r < 4; ++r) {
      float mx = fmaxf(fmaxf(s4[0][r], s4[1][r]), fmaxf(s4[2][r], s4[3][r])) * scale;
      #pragma unroll
      for (int off = 1; off <= 8; off <<= 1) mx = fmaxf(mx, __shfl_xor(mx, off));
      float nm = fmaxf(m_run[r], mx);
      f_[r] = __expf(m_run[r] - nm);
      m_run[r] = nm;
    }
    float p[4][4];
    #pragma unroll
    for (int kt = 0; kt < 4; ++kt)
      #pragma unroll
      for (int r = 0; r < 4; ++r)
        p[kt][r] = __expf(s4[kt][r]*scale - m_run[r]);
    #pragma unroll
    for (int r = 0; r < 4; ++r) {
      float sum = p[0][r] + p[1][r] + p[2][r] + p[3][r];
      #pragma unroll
      for (int off = 1; off <= 8; off <<= 1) sum += __shfl_xor(sum, off);
      l_run[r] = l_run[r]*f_[r] + sum;
    }
    #pragma unroll
    for (int dt = 0; dt < 8; ++dt) {
      f32x4 t = o_[dt];
      t[0]*=f_[0]; t[1]*=f_[1]; t[2]*=f_[2]; t[3]*=f_[3];
      o_[dt] = t;
    }

    __builtin_amdgcn_s_barrier();          // B1: all QK reads of Ks[cur] done
    // ---- P -> dead Ks[cur] (wave-private region, XOR chunk^(q&7)) ----
    u16* pw = Ks + cur*8192 + w*1024;
    #pragma unroll
    for (int kt = 0; kt < 4; ++kt)
      #pragma unroll
      for (int r = 0; r < 4; ++r) {
        int q = l4*4 + r;
        pw[q*64 + (((kt*2 + (l15>>3)) ^ (q&7))<<3) + (l15&7)] = f2bf(p[kt][r]);
      }
    // ---- PV (P read is wave-private: intra-wave LDS ordering suffices) ----
    #pragma unroll
    for (int ks = 0; ks < 2; ++ks) {
      short8 pa = *(const short8*)((const char*)pw + l15*128 + (((ks*4 + l4) ^ (l15&7))<<4));
      __builtin_amdgcn_s_setprio(1);
      #pragma unroll
      for (int dt = 0; dt < 8; ++dt) {
        int d = dt*16 + l15;
        short8 vf = *(const short8*)(VtB + d*128 + (((ks*4 + l4) ^ (d&7))<<4));
        o_[dt] = __builtin_amdgcn_mfma_f32_16x16x32_bf16(pa, vf, o_[dt], 0, 0, 0);
      }
      __builtin_amdgcn_s_setprio(0);
    }
  }
  #undef STAGE_CHUNK

  // ---- epilogue ----
  float inv[4];
  #pragma unroll
  for (int r = 0; r < 4; ++r) inv[r] = 1.0f / l_run[r];
  int nt = n >> 4, nh2 = (n >> 2) & 3, nw = n & 3;
  #pragma unroll
  for (int dt = 0; dt < 8; ++dt) {
    int d = dt*16 + l15;
    int col = h*128 + d;
    #pragma unroll
    for (int r = 0; r < 4; ++r) {
      float val = o_[dt][r] * inv[r];
      int q = qt + l4*4 + r;
      if (q < 256) {
        int wt = q >> 6, wh = (q >> 3) & 7, ww = q & 7;
        int rg = ((nt*4 + wt)*32 + (nh2*8 + wh))*32 + (nw*8 + ww);
        vo[(size_t)rg*2048 + col] = f2bf(val);
      } else {
        atomicAdd(to_acc + (size_t)(q - 256)*2048 + col, val * (1.0f/32.0f));
      }
    }
  }
}

// ---------------- host launch ----------------
extern "C" void kernel_launch(void* const* d_in, const int* in_sizes, int n_in,
                              void* d_out, int out_size, void* d_ws, size_t ws_size,
                              hipStream_t stream) {
  const float* vid    = (const float*)d_in[0];
  const float* txt    = (const float*)d_in[1];
  const float* Wqkv_v = (const float*)d_in[2];
  const float* bqkv_v = (const float*)d_in[3];
  const float* Wqkv_t = (const float*)d_in[4];
  const float* bqkv_t = (const float*)d_in[5];
  const float* Wo_v   = (const float*)d_in[6];
  const float* bo_v   = (const float*)d_in[7];
  const float* Wo_t   = (const float*)d_in[8];
  const float* bo_t   = (const float*)d_in[9];
  const float* gq_v   = (const float*)d_in[10];
  const float* gk_v   = (const float*)d_in[11];
  const float* gq_t   = (const float*)d_in[12];
  const float* gk_t   = (const float*)d_in[13];
  float* out = (float*)d_out;

  char* p = (char*)d_ws;
  u16* vid_bf   = (u16*)p;  p += 8192ull*2048*2;
  u16* txt_bf   = (u16*)p;  p += 256ull*2048*2;
  u16* Wqkv_v_t = (u16*)p;  p += 6144ull*2048*2;
  u16* Wqkv_t_t = (u16*)p;  p += 6144ull*2048*2;
  u16* Wo_v_t   = (u16*)p;  p += 2048ull*2048*2;
  u16* Wo_t_t   = (u16*)p;  p += 2048ull*2048*2;
  u16* vq_w     = (u16*)p;  p += 32ull*16*256*128*2;
  u16* vk_w     = (u16*)p;  p += 32ull*16*256*128*2;
  u16* vv_w     = (u16*)p;  p += 32ull*16*256*128*2;   // [win][head][key][d]
  u16* tq_w     = (u16*)p;  p += 16ull*256*128*2;
  u16* tk_w     = (u16*)p;  p += 16ull*256*128*2;
  u16* tv_w     = (u16*)p;  p += 16ull*256*128*2;      // [head][key][d]
  u16* vo_pre   = (u16*)p;  p += 8192ull*2048*2;
  float* to_pre = (float*)p; p += 256ull*2048*4;
  u16* to_bf    = (u16*)p;  p += 256ull*2048*2;
  // vvT/tvT alias vid_bf's region (vid_bf is dead after the QKV gemm256)
  u16* vvT = vid_bf;                                    // [win*16+h][128 d][256 key]
  u16* tvT = vid_bf + 512ull*128*256;                   // [h][128 d][256 key]

  hipMemsetAsync(to_pre, 0, 256ull*2048*4, stream);

  // converts
  conv_f32_bf16<<<dim3(16384), dim3(256), 0, stream>>>(vid, vid_bf, 8192*2048/4);
  conv_f32_bf16<<<dim3(512),   dim3(256), 0, stream>>>(txt, txt_bf, 256*2048/4);
  tconv_kernel<<<dim3(192,64), dim3(32,8), 0, stream>>>(Wqkv_v, Wqkv_v_t, 2048, 6144);
  tconv_kernel<<<dim3(192,64), dim3(32,8), 0, stream>>>(Wqkv_t, Wqkv_t_t, 2048, 6144);
  tconv_kernel<<<dim3(64,64),  dim3(32,8), 0, stream>>>(Wo_v,   Wo_v_t,   2048, 2048);
  tconv_kernel<<<dim3(64,64),  dim3(32,8), 0, stream>>>(Wo_t,   Wo_t_t,   2048, 2048);

  // QKV projections (coalesced scatter, V un-transposed)
  gemm256<0><<<dim3(24,32), dim3(512), 0, stream>>>(vid_bf, Wqkv_v_t, bqkv_v,
      vq_w, vk_w, vv_w, nullptr, 0, 8192, NQKV, DIM);
  gemm128<1><<<dim3(48,2),  dim3(256), 0, stream>>>(txt_bf, Wqkv_t_t, bqkv_t,
      tq_w, tk_w, tv_w, nullptr, 0, 256, NQKV, DIM);

  // V transpose (after QKV gemms; vvT aliases vid_bf which is now dead)
  vtrans_kernel<<<dim3(512,4), dim3(256), 0, stream>>>(vv_w, vvT);
  vtrans_kernel<<<dim3(16,4),  dim3(256), 0, stream>>>(tv_w, tvT);

  // RMSNorm for K only (Q fused into attention)
  rms_kernel<<<dim3(32768), dim3(256), 0, stream>>>(vk_w, gk_v, 32*16*256);
  rms_kernel<<<dim3(1024),  dim3(256), 0, stream>>>(tk_w, gk_t, 16*256);

  // attention (2048 blocks, XCD-chunked: 4 q-quarters of each head adjacent)
  attn_kernel<<<dim3(2048), dim3(512), 0, stream>>>(vq_w, vk_w, vvT, tq_w, tk_w, tvT,
                                                    gq_v, gq_t, vo_pre, to_pre);

  // text accum -> bf16
  conv_f32_bf16<<<dim3(512), dim3(256), 0, stream>>>(to_pre, to_bf, 256*2048/4);

  // output projections
  gemm256<2><<<dim3(8,32), dim3(512), 0, stream>>>(vo_pre, Wo_v_t, bo_v,
      nullptr, nullptr, nullptr, out, 2048, 8192, 2048, 2048);
  gemm128<2><<<dim3(16,2), dim3(256), 0, stream>>>(to_bf, Wo_t_t, bo_t,
      nullptr, nullptr, nullptr, out + 16777216, 2048, 256, 2048, 2048);
}

// Round 10
// 608.156 us; speedup vs baseline: 1.0594x; 1.0594x over previous
//
#include <hip/hip_runtime.h>

typedef unsigned short u16;
typedef unsigned int   u32;
typedef __attribute__((ext_vector_type(8))) short short8;   // 8 x bf16 (4 VGPRs)
typedef __attribute__((ext_vector_type(4))) float f32x4;    // MFMA accum

// ---------------- helpers ----------------
__device__ __forceinline__ u16 f2bf(float f) {
  union { float f; u32 u; } v; v.f = f;
  u32 r = v.u + 0x7fffu + ((v.u >> 16) & 1u);   // RNE
  return (u16)(r >> 16);
}
__device__ __forceinline__ float bf2f(u32 bits) {
  union { u32 u; float f; } v; v.u = bits << 16; return v.f;
}
// async global->LDS, 16B per lane. LDS dest is WAVE-UNIFORM base; HW adds lane*16.
__device__ __forceinline__ void gl_lds16(const u16* g, u16* l) {
  __builtin_amdgcn_global_load_lds(
      (const __attribute__((address_space(1))) void*)g,
      (__attribute__((address_space(3))) void*)l, 16, 0, 0);
}

// ---------------- problem constants ----------------
static constexpr int DIM  = 2048;
static constexpr int NQKV = 6144;

// ---------------- f32 -> bf16 convert (4 elems/thread) ----------------
__global__ __launch_bounds__(256) void conv_f32_bf16(const float* __restrict__ in,
                                                     u16* __restrict__ out, int n4) {
  int id = blockIdx.x * 256 + threadIdx.x;
  if (id >= n4) return;
  float4 v = ((const float4*)in)[id];
  u32 lo = (u32)f2bf(v.x) | ((u32)f2bf(v.y) << 16);
  u32 hi = (u32)f2bf(v.z) | ((u32)f2bf(v.w) << 16);
  ((uint2*)out)[id] = make_uint2(lo, hi);
}

// ---------------- transpose + convert: W[K][N] f32 -> Wt[N][K] bf16 ----------------
__global__ void tconv_kernel(const float* __restrict__ W, u16* __restrict__ Wt, int K, int N) {
  __shared__ float t[32][33];
  int tx = threadIdx.x, ty = threadIdx.y;           // 32 x 8
  int n0 = blockIdx.x * 32, k0 = blockIdx.y * 32;
  #pragma unroll
  for (int i = 0; i < 4; ++i)
    t[ty + i*8][tx] = W[(size_t)(k0 + ty + i*8) * N + n0 + tx];
  __syncthreads();
  #pragma unroll
  for (int i = 0; i < 4; ++i)
    Wt[(size_t)(n0 + ty + i*8) * K + k0 + tx] = f2bf(t[tx][ty + i*8]);
}

// ---------------- RMSNorm in-place on bf16 rows of 128 (1 wave / row) ----------------
__global__ __launch_bounds__(256) void rms_kernel(u16* __restrict__ x,
                                                  const float* __restrict__ g, int nrows) {
  int w = threadIdx.x >> 6, lane = threadIdx.x & 63;
  int rid = blockIdx.x * 4 + w;
  if (rid >= nrows) return;
  u32* row = (u32*)x + (size_t)rid * 64;
  u32 u = row[lane];
  float f0 = bf2f(u & 0xffffu), f1 = bf2f(u >> 16);
  float s = f0*f0 + f1*f1;
  #pragma unroll
  for (int off = 1; off <= 32; off <<= 1) s += __shfl_xor(s, off);
  float r = rsqrtf(s * (1.0f/128.0f) + 1e-6f);
  float g0 = g[lane*2], g1 = g[lane*2+1];
  row[lane] = (u32)f2bf(f0*r*g0) | ((u32)f2bf(f1*r*g1) << 16);
}

// ---------------- V transpose: [nh][256 key][128 d] -> [nh][128 d][256 key] ----------
__global__ __launch_bounds__(256)
void vtrans_kernel(const u16* __restrict__ src, u16* __restrict__ dst) {
  __shared__ u16 t[64][130];
  int nh = blockIdx.x, k0 = blockIdx.y * 64;
  const u16* s = src + ((size_t)nh*256 + k0)*128;
  u16* d = dst + (size_t)nh*128*256 + k0;
  int tid = threadIdx.x;
  #pragma unroll
  for (int it = 0; it < 4; ++it) {
    int c = tid + it*256;
    int row = c >> 4, ch = c & 15;          // row 0..63, 16B chunk 0..15
    short8 v = *(const short8*)(s + row*128 + ch*8);
    u32* dst32 = (u32*)&t[row][ch*8];
    const u32* v32 = (const u32*)&v;
    dst32[0] = v32[0]; dst32[1] = v32[1]; dst32[2] = v32[2]; dst32[3] = v32[3];
  }
  __syncthreads();
  #pragma unroll
  for (int it = 0; it < 4; ++it) {
    int c = tid + it*256;
    int dr = c >> 3, kg = c & 7;            // d-row 0..127, key-group 0..7
    short8 v;
    #pragma unroll
    for (int j = 0; j < 8; ++j) v[j] = (short)t[kg*8+j][dr];
    *(short8*)(d + (size_t)dr*256 + kg*8) = v;
  }
}

// ---------------- text-output reduction: mean over 32 windows of bf16 partials ------
// part[win][256][2048] bf16 -> to_bf[256][2048] bf16 (x 1/32).
__global__ __launch_bounds__(256)
void reduce_txt(const u16* __restrict__ part, u16* __restrict__ to_bf) {
  int row = blockIdx.x, c8 = threadIdx.x;   // 256 blocks x 256 threads (8 cols each)
  const u16* p = part + (size_t)row*2048 + c8*8;
  float s[8] = {};
  #pragma unroll 4
  for (int wn = 0; wn < 32; ++wn) {
    short8 v = *(const short8*)(p + (size_t)wn*256*2048);
    #pragma unroll
    for (int j = 0; j < 8; ++j) s[j] += bf2f((u16)v[j]);
  }
  short8 o;
  #pragma unroll
  for (int j = 0; j < 8; ++j) o[j] = (short)f2bf(s[j] * (1.0f/32.0f));
  *(short8*)(to_bf + (size_t)row*2048 + c8*8) = o;
}

// ============== 256x256-tile pipelined GEMM, BK=32, 4-buffer ring, 8 waves ==========
// (R6 known-good form: top-of-tile counted vmcnt + single barrier, 0 bank conflicts)
template<int EPI>
__global__ __launch_bounds__(512, 2)
void gemm256(const u16* __restrict__ A, const u16* __restrict__ Bt,
             const float* __restrict__ bias,
             u16* __restrict__ o0, u16* __restrict__ o1, u16* __restrict__ o2,
             float* __restrict__ of, int ldo, int M, int N, int K)
{
  __shared__ __align__(16) u16 As[4][256*32];
  __shared__ __align__(16) u16 Bs[4][256*32];
  const int NT = K >> 5;
  int tid = threadIdx.x, lane = tid & 63, w = tid >> 6;
  int l15 = lane & 15, l4 = lane >> 4;
  int wm = w >> 2, wn = w & 3;                   // 2M x 4N wave grid

  int nbx = gridDim.x;
  int nwg = nbx * gridDim.y;
  int bid = blockIdx.y * nbx + blockIdx.x;
  int cpx = nwg >> 3;
  int swz = (bid & 7) * cpx + (bid >> 3);
  int n0 = (swz % nbx) * 256, m0 = (swz / nbx) * 256;

  int srow = tid >> 2, skc = (tid & 3) ^ ((tid >> 3) & 3);
  const u16* aS = A  + (size_t)(m0 + srow) * K + skc * 8;
  const u16* bS = Bt + (size_t)(n0 + srow) * K + skc * 8;
  const size_t halfStride = 128 * (size_t)K;
  const int ldsBase = w * 512;

  #define STAGE_A(slot, tt, half) \
    gl_lds16(aS + (size_t)(tt)*32 + (half)*halfStride, &As[slot][(half)*4096 + ldsBase])
  #define STAGE_B(slot, tt, half) \
    gl_lds16(bS + (size_t)(tt)*32 + (half)*halfStride, &Bs[slot][(half)*4096 + ldsBase])

  #pragma unroll
  for (int pt = 0; pt < 3; ++pt) {
    STAGE_A(pt, pt, 0); STAGE_A(pt, pt, 1);
    STAGE_B(pt, pt, 0); STAGE_B(pt, pt, 1);
  }

  f32x4 acc[8][4] = {};

  for (int t = 0; t < NT; ++t) {
    if (t < NT - 2)       asm volatile("s_waitcnt vmcnt(8)" ::: "memory");
    else if (t == NT - 2) asm volatile("s_waitcnt vmcnt(4)" ::: "memory");
    else                  asm volatile("s_waitcnt vmcnt(0)" ::: "memory");
    __builtin_amdgcn_s_barrier();
    asm volatile("" ::: "memory");

    const u16* ab = As[t & 3];
    const u16* bb = Bs[t & 3];
    bool st = (t + 3 < NT);
    int slot = (t + 3) & 3;

    short8 bf_[4];
    #pragma unroll
    for (int j = 0; j < 4; ++j) {
      int rb = wn*64 + j*16 + l15;
      bf_[j] = *(const short8*)((const char*)bb + rb*64 + ((l4 ^ ((rb>>1)&3))*16));
    }

    short8 af[4];
    #pragma unroll
    for (int i = 0; i < 4; ++i) {
      int ra = wm*128 + i*16 + l15;
      af[i] = *(const short8*)((const char*)ab + ra*64 + ((l4 ^ ((ra>>1)&3))*16));
    }
    if (st) { STAGE_A(slot, t+3, 0); STAGE_A(slot, t+3, 1); }
    __builtin_amdgcn_s_setprio(1);
    #pragma unroll
    for (int i = 0; i < 4; ++i)
      #pragma unroll
      for (int j = 0; j < 4; ++j)
        acc[i][j] = __builtin_amdgcn_mfma_f32_16x16x32_bf16(af[i], bf_[j], acc[i][j], 0, 0, 0);
    __builtin_amdgcn_s_setprio(0);

    #pragma unroll
    for (int i = 0; i < 4; ++i) {
      int ra = wm*128 + 64 + i*16 + l15;
      af[i] = *(const short8*)((const char*)ab + ra*64 + ((l4 ^ ((ra>>1)&3))*16));
    }
    if (st) { STAGE_B(slot, t+3, 0); STAGE_B(slot, t+3, 1); }
    __builtin_amdgcn_s_setprio(1);
    #pragma unroll
    for (int i = 0; i < 4; ++i)
      #pragma unroll
      for (int j = 0; j < 4; ++j)
        acc[4+i][j] = __builtin_amdgcn_mfma_f32_16x16x32_bf16(af[i], bf_[j], acc[4+i][j], 0, 0, 0);
    __builtin_amdgcn_s_setprio(0);
  }
  #undef STAGE_A
  #undef STAGE_B

  #pragma unroll
  for (int i = 0; i < 8; ++i)
    #pragma unroll
    for (int j = 0; j < 4; ++j)
      #pragma unroll
      for (int r = 0; r < 4; ++r) {
        int m = m0 + wm*128 + i*16 + l4*4 + r;
        int n = n0 + wn*64  + j*16 + l15;
        float v = acc[i][j][r] + bias[n];
        if (EPI == 0) {           // vid QKV -> windowed [win][head][p][128]
          int which = n >> 11, head = (n >> 7) & 15, d = n & 127;
          int t = m >> 10, hh = (m >> 5) & 31, ww = m & 31;
          int win = ((t>>2)<<4) + ((hh>>3)<<2) + (ww>>3);
          int p   = ((t&3)<<6) + ((hh&7)<<3) + (ww&7);
          u16* dst = which == 0 ? o0 : (which == 1 ? o1 : o2);
          dst[((size_t)(win*16 + head)*256 + p)*128 + d] = f2bf(v);
        } else {                  // plain f32
          of[(size_t)m * ldo + n] = v;
        }
      }
}

// ======= 128x128-tile pipelined GEMM, BK=32, 4-slot ring, 4 waves (txt matrices) ====
// Same counted-vmcnt ring as gemm256, halved geometry. 64 KB LDS -> 2 blocks/CU.
template<int EPI>
__global__ __launch_bounds__(256, 2)
void gemm128p(const u16* __restrict__ A, const u16* __restrict__ Bt,
              const float* __restrict__ bias,
              u16* __restrict__ o0, u16* __restrict__ o1, u16* __restrict__ o2,
              float* __restrict__ of, int ldo, int M, int N, int K)
{
  __shared__ __align__(16) u16 As[4][128*32];
  __shared__ __align__(16) u16 Bs[4][128*32];
  const int NT = K >> 5;
  int tid = threadIdx.x, lane = tid & 63, w = tid >> 6;
  int l15 = lane & 15, l4 = lane >> 4;
  int m0 = blockIdx.y * 128, n0 = blockIdx.x * 128;
  int wr = (w >> 1) * 64, wc = (w & 1) * 64;

  int srow = tid >> 2, skc = (tid & 3) ^ ((tid >> 3) & 3);
  const u16* aS = A  + (size_t)(m0 + srow) * K + skc * 8;
  const u16* bS = Bt + (size_t)(n0 + srow) * K + skc * 8;
  const size_t halfStride = 64 * (size_t)K;
  const int ldsBase = w * 512;                  // u16; wave covers 1KB per half

  #define STAGE_A(slot, tt, half) \
    gl_lds16(aS + (size_t)(tt)*32 + (half)*halfStride, &As[slot][(half)*2048 + ldsBase])
  #define STAGE_B(slot, tt, half) \
    gl_lds16(bS + (size_t)(tt)*32 + (half)*halfStride, &Bs[slot][(half)*2048 + ldsBase])

  #pragma unroll
  for (int pt = 0; pt < 3; ++pt) {
    STAGE_A(pt, pt, 0); STAGE_A(pt, pt, 1);
    STAGE_B(pt, pt, 0); STAGE_B(pt, pt, 1);
  }

  f32x4 acc[4][4] = {};

  for (int t = 0; t < NT; ++t) {
    if (t < NT - 2)       asm volatile("s_waitcnt vmcnt(8)" ::: "memory");
    else if (t == NT - 2) asm volatile("s_waitcnt vmcnt(4)" ::: "memory");
    else                  asm volatile("s_waitcnt vmcnt(0)" ::: "memory");
    __builtin_amdgcn_s_barrier();
    asm volatile("" ::: "memory");

    const u16* ab = As[t & 3];
    const u16* bb = Bs[t & 3];
    bool st = (t + 3 < NT);
    int slot = (t + 3) & 3;

    short8 af[4], bfr[4];
    #pragma unroll
    for (int i = 0; i < 4; ++i) {
      int ra = wr + i*16 + l15;
      af[i]  = *(const short8*)((const char*)ab + ra*64 + ((l4 ^ ((ra>>1)&3))*16));
      int rb = wc + i*16 + l15;
      bfr[i] = *(const short8*)((const char*)bb + rb*64 + ((l4 ^ ((rb>>1)&3))*16));
    }
    if (st) {
      STAGE_A(slot, t+3, 0); STAGE_A(slot, t+3, 1);
      STAGE_B(slot, t+3, 0); STAGE_B(slot, t+3, 1);
    }
    __builtin_amdgcn_s_setprio(1);
    #pragma unroll
    for (int i = 0; i < 4; ++i)
      #pragma unroll
      for (int j = 0; j < 4; ++j)
        acc[i][j] = __builtin_amdgcn_mfma_f32_16x16x32_bf16(af[i], bfr[j], acc[i][j], 0, 0, 0);
    __builtin_amdgcn_s_setprio(0);
  }
  #undef STAGE_A
  #undef STAGE_B

  #pragma unroll
  for (int i = 0; i < 4; ++i)
    #pragma unroll
    for (int j = 0; j < 4; ++j)
      #pragma unroll
      for (int r = 0; r < 4; ++r) {
        int m = m0 + wr + i*16 + l4*4 + r;
        int n = n0 + wc + j*16 + l15;
        float v = acc[i][j][r] + bias[n];
        if (EPI == 1) {           // txt QKV -> [head][p][128]
          int which = n >> 11, head = (n >> 7) & 15, d = n & 127;
          u16* dst = which == 0 ? o0 : (which == 1 ? o1 : o2);
          dst[((size_t)head*256 + m)*128 + d] = f2bf(v);
        } else {                  // plain f32
          of[(size_t)m * ldo + n] = v;
        }
      }
}

// ---------------- fused windowed attention: no atomics, bf16 window-partials --------
// 2048 blocks, XCD-chunked (4 q-quarters of each (win,head) consecutive per XCD).
// 8 waves x 16 q-rows. K/V double-buffered (64 KB), P written into dead K-buffer.
// Text rows -> to_part[win][row][col] bf16 (plain stores; reduced by reduce_txt).
__global__ __launch_bounds__(512, 4)
void attn_kernel(const u16* __restrict__ vq, const u16* __restrict__ vk, const u16* __restrict__ vv,
                 const u16* __restrict__ tq, const u16* __restrict__ tk, const u16* __restrict__ tv,
                 const float* __restrict__ gq_v, const float* __restrict__ gq_t,
                 u16* __restrict__ vo, u16* __restrict__ to_part)
{
  __shared__ __align__(16) u16 Ks[2*64*128];    // [buf][key][d] swizzled; cur reused for P
  __shared__ __align__(16) u16 Vt[2*128*64];    // [buf][d][key] swizzled
  int tid = threadIdx.x, lane = tid & 63, w = tid >> 6;
  int l15 = lane & 15, l4 = lane >> 4;
  int bid = blockIdx.x;
  int logical = (bid & 7) * 256 + (bid >> 3);
  int nh_ = logical >> 2, qq = logical & 3;
  int h = nh_ & 15;
  int n = nh_ >> 4;
  int qt = qq * 128 + w * 16;

  // ---- Q load + fused RMSNorm ----
  const u16* Qb; const float* gq;
  if (qt < 256) { Qb = vq + ((size_t)nh_*256 + qt)*128; gq = gq_v; }
  else          { Qb = tq + ((size_t)h  *256 + (qt-256))*128; gq = gq_t; }
  short8 qf[4];
  float qv[4][8];
  float ss = 0.f;
  #pragma unroll
  for (int dt = 0; dt < 4; ++dt) {
    qf[dt] = *(const short8*)(Qb + l15*128 + l4*8 + dt*32);
    #pragma unroll
    for (int j = 0; j < 8; ++j) {
      float f = bf2f((u16)qf[dt][j]);
      qv[dt][j] = f; ss += f*f;
    }
  }
  ss += __shfl_xor(ss, 16); ss += __shfl_xor(ss, 32);
  float rr = rsqrtf(ss * (1.0f/128.0f) + 1e-6f);
  #pragma unroll
  for (int dt = 0; dt < 4; ++dt) {
    float4 g0 = *(const float4*)(gq + l4*8 + dt*32);
    float4 g1 = *(const float4*)(gq + l4*8 + dt*32 + 4);
    qf[dt][0] = (short)f2bf(qv[dt][0]*rr*g0.x); qf[dt][1] = (short)f2bf(qv[dt][1]*rr*g0.y);
    qf[dt][2] = (short)f2bf(qv[dt][2]*rr*g0.z); qf[dt][3] = (short)f2bf(qv[dt][3]*rr*g0.w);
    qf[dt][4] = (short)f2bf(qv[dt][4]*rr*g1.x); qf[dt][5] = (short)f2bf(qv[dt][5]*rr*g1.y);
    qf[dt][6] = (short)f2bf(qv[dt][6]*rr*g1.z); qf[dt][7] = (short)f2bf(qv[dt][7]*rr*g1.w);
  }

  // ---- staging geometry (global_load_lds: wave-uniform LDS dest, per-lane src) ----
  int oK0 = w*1024 + lane*16, oK1 = oK0 + 8192;
  int kr0 = oK0 >> 8, kc0 = ((oK0 >> 4) & 15) ^ (kr0 & 7);
  int kr1 = oK1 >> 8, kc1 = ((oK1 >> 4) & 15) ^ (kr1 & 7);
  int vd0 = oK0 >> 7, vc0 = ((oK0 >> 4) & 7) ^ (vd0 & 7);
  int vd1 = oK1 >> 7, vc1 = ((oK1 >> 4) & 7) ^ (vd1 & 7);

  f32x4 o_[8] = {};
  float m_run[4] = {-1e30f,-1e30f,-1e30f,-1e30f};
  float l_run[4] = {0.f,0.f,0.f,0.f};
  const float scale = 0.08838834764831845f;

  #define STAGE_CHUNK(cc, buf)                                                        \
    {                                                                                 \
      int kb = (cc) * 64;                                                             \
      const u16* Kc; const u16* Vb; int vkb;                                          \
      if (kb < 256) { Kc = vk + ((size_t)nh_*256 + kb)*128;                           \
                      Vb = vv + (size_t)nh_*128*256; vkb = kb; }                      \
      else          { Kc = tk + ((size_t)h*256 + (kb-256))*128;                       \
                      Vb = tv + (size_t)h*128*256; vkb = kb - 256; }                  \
      gl_lds16(Kc + kr0*128 + kc0*8, Ks + (buf)*8192 + w*512);                        \
      gl_lds16(Kc + kr1*128 + kc1*8, Ks + (buf)*8192 + w*512 + 4096);                 \
      gl_lds16(Vb + (size_t)vd0*256 + vkb + vc0*8, Vt + (buf)*8192 + w*512);          \
      gl_lds16(Vb + (size_t)vd1*256 + vkb + vc1*8, Vt + (buf)*8192 + w*512 + 4096);   \
    }

  // prologue: stage chunk 0
  STAGE_CHUNK(0, 0);

  for (int c = 0; c < 8; ++c) {
    int cur = c & 1;
    __builtin_amdgcn_s_barrier();          // A: prev chunk's readers of ^cur done
    if (c < 7) STAGE_CHUNK(c + 1, cur ^ 1);
    if (c < 7) asm volatile("s_waitcnt vmcnt(4)" ::: "memory");
    else       asm volatile("s_waitcnt vmcnt(0)" ::: "memory");
    __builtin_amdgcn_s_barrier();          // B0: all waves' chunk-c loads visible
    const char* KsB = (const char*)(Ks + cur*8192);
    const char* VtB = (const char*)(Vt + cur*8192);

    // ---- S = Q K^T ----
    f32x4 s4[4];
    __builtin_amdgcn_s_setprio(1);
    #pragma unroll
    for (int kt = 0; kt < 4; ++kt) {
      f32x4 sa = {0.f,0.f,0.f,0.f};
      int key = kt*16 + l15;
      #pragma unroll
      for (int dt = 0; dt < 4; ++dt) {
        int c16b = l4 + dt*4;
        short8 kf = *(const short8*)(KsB + key*256 + (((c16b ^ (key&7)))*16));
        sa = __builtin_amdgcn_mfma_f32_16x16x32_bf16(qf[dt], kf, sa, 0, 0, 0);
      }
      s4[kt] = sa;
    }
    __builtin_amdgcn_s_setprio(0);

    // ---- online softmax ----
    float f_[4];
    #pragma unroll
    for (int r = 0; r < 4; ++r) {
      float mx = fmaxf(fmaxf(s4[0][r], s4[1][r]), fmaxf(s4[2][r], s4[3][r])) * scale;
      #pragma unroll
      for (int off = 1; off <= 8; off <<= 1) mx = fmaxf(mx, __shfl_xor(mx, off));
      float nm = fmaxf(m_run[r], mx);
      f_[r] = __expf(m_run[r] - nm);
      m_run[r] = nm;
    }
    float p[4][4];
    #pragma unroll
    for (int kt = 0; kt < 4; ++kt)
      #pragma unroll
      for (int r = 0; r < 4; ++r)
        p[kt][r] = __expf(s4[kt][r]*scale - m_run[r]);
    #pragma unroll
    for (int r = 0; r < 4; ++r) {
      float sum = p[0][r] + p[1][r] + p[2][r] + p[3][r];
      #pragma unroll
      for (int off = 1; off <= 8; off <<= 1) sum += __shfl_xor(sum, off);
      l_run[r] = l_run[r]*f_[r] + sum;
    }
    #pragma unroll
    for (int dt = 0; dt < 8; ++dt) {
      f32x4 t = o_[dt];
      t[0]*=f_[0]; t[1]*=f_[1]; t[2]*=f_[2]; t[3]*=f_[3];
      o_[dt] = t;
    }

    __builtin_amdgcn_s_barrier();          // B1: all QK reads of Ks[cur] done
    // ---- P -> dead Ks[cur] (wave-private region, XOR chunk^(q&7)) ----
    u16* pw = Ks + cur*8192 + w*1024;
    #pragma unroll
    for (int kt = 0; kt < 4; ++kt)
      #pragma unroll
      for (int r = 0; r < 4; ++r) {
        int q = l4*4 + r;
        pw[q*64 + (((kt*2 + (l15>>3)) ^ (q&7))<<3) + (l15&7)] = f2bf(p[kt][r]);
      }
    // ---- PV (P read is wave-private: intra-wave LDS ordering suffices) ----
    #pragma unroll
    for (int ks = 0; ks < 2; ++ks) {
      short8 pa = *(const short8*)((const char*)pw + l15*128 + (((ks*4 + l4) ^ (l15&7))<<4));
      __builtin_amdgcn_s_setprio(1);
      #pragma unroll
      for (int dt = 0; dt < 8; ++dt) {
        int d = dt*16 + l15;
        short8 vf = *(const short8*)(VtB + d*128 + (((ks*4 + l4) ^ (d&7))<<4));
        o_[dt] = __builtin_amdgcn_mfma_f32_16x16x32_bf16(pa, vf, o_[dt], 0, 0, 0);
      }
      __builtin_amdgcn_s_setprio(0);
    }
  }
  #undef STAGE_CHUNK

  // ---- epilogue ----
  float inv[4];
  #pragma unroll
  for (int r = 0; r < 4; ++r) inv[r] = 1.0f / l_run[r];
  int nt = n >> 4, nh2 = (n >> 2) & 3, nw = n & 3;
  #pragma unroll
  for (int dt = 0; dt < 8; ++dt) {
    int d = dt*16 + l15;
    int col = h*128 + d;
    #pragma unroll
    for (int r = 0; r < 4; ++r) {
      float val = o_[dt][r] * inv[r];
      int q = qt + l4*4 + r;
      if (q < 256) {
        int wt = q >> 6, wh = (q >> 3) & 7, ww = q & 7;
        int rg = ((nt*4 + wt)*32 + (nh2*8 + wh))*32 + (nw*8 + ww);
        vo[(size_t)rg*2048 + col] = f2bf(val);
      } else {
        to_part[((size_t)n*256 + (q - 256))*2048 + col] = f2bf(val);
      }
    }
  }
}

// ---------------- host launch ----------------
extern "C" void kernel_launch(void* const* d_in, const int* in_sizes, int n_in,
                              void* d_out, int out_size, void* d_ws, size_t ws_size,
                              hipStream_t stream) {
  const float* vid    = (const float*)d_in[0];
  const float* txt    = (const float*)d_in[1];
  const float* Wqkv_v = (const float*)d_in[2];
  const float* bqkv_v = (const float*)d_in[3];
  const float* Wqkv_t = (const float*)d_in[4];
  const float* bqkv_t = (const float*)d_in[5];
  const float* Wo_v   = (const float*)d_in[6];
  const float* bo_v   = (const float*)d_in[7];
  const float* Wo_t   = (const float*)d_in[8];
  const float* bo_t   = (const float*)d_in[9];
  const float* gq_v   = (const float*)d_in[10];
  const float* gk_v   = (const float*)d_in[11];
  const float* gq_t   = (const float*)d_in[12];
  const float* gk_t   = (const float*)d_in[13];
  float* out = (float*)d_out;

  char* p = (char*)d_ws;
  u16* vid_bf   = (u16*)p;  p += 8192ull*2048*2;
  u16* txt_bf   = (u16*)p;  p += 256ull*2048*2;
  u16* Wqkv_v_t = (u16*)p;  p += 6144ull*2048*2;
  u16* Wqkv_t_t = (u16*)p;  p += 6144ull*2048*2;
  u16* Wo_v_t   = (u16*)p;  p += 2048ull*2048*2;
  u16* Wo_t_t   = (u16*)p;  p += 2048ull*2048*2;
  u16* vq_w     = (u16*)p;  p += 32ull*16*256*128*2;
  u16* vk_w     = (u16*)p;  p += 32ull*16*256*128*2;
  u16* vv_w     = (u16*)p;  p += 32ull*16*256*128*2;   // [win][head][key][d]
  u16* tq_w     = (u16*)p;  p += 16ull*256*128*2;
  u16* tk_w     = (u16*)p;  p += 16ull*256*128*2;
  u16* tv_w     = (u16*)p;  p += 16ull*256*128*2;      // [head][key][d]
  u16* vo_pre   = (u16*)p;  p += 8192ull*2048*2;
  float* to_pre = (float*)p; p += 256ull*2048*4;       // (unused now)
  u16* to_bf    = (u16*)p;  p += 256ull*2048*2;
  // vvT/tvT alias vid_bf+txt_bf (dead after the QKV gemms)
  u16* vvT = vid_bf;                                    // [win*16+h][128 d][256 key]
  u16* tvT = vid_bf + 512ull*128*256;                   // [h][128 d][256 key]
  // to_part aliases Wqkv_v_t/Wqkv_t_t (dead after the QKV gemms): 32x256x2048 bf16 = 33.6 MB
  u16* to_part = Wqkv_v_t;
  (void)to_pre;

  // converts
  conv_f32_bf16<<<dim3(16384), dim3(256), 0, stream>>>(vid, vid_bf, 8192*2048/4);
  conv_f32_bf16<<<dim3(512),   dim3(256), 0, stream>>>(txt, txt_bf, 256*2048/4);
  tconv_kernel<<<dim3(192,64), dim3(32,8), 0, stream>>>(Wqkv_v, Wqkv_v_t, 2048, 6144);
  tconv_kernel<<<dim3(192,64), dim3(32,8), 0, stream>>>(Wqkv_t, Wqkv_t_t, 2048, 6144);
  tconv_kernel<<<dim3(64,64),  dim3(32,8), 0, stream>>>(Wo_v,   Wo_v_t,   2048, 2048);
  tconv_kernel<<<dim3(64,64),  dim3(32,8), 0, stream>>>(Wo_t,   Wo_t_t,   2048, 2048);

  // QKV projections (coalesced scatter, V un-transposed)
  gemm256<0><<<dim3(24,32), dim3(512), 0, stream>>>(vid_bf, Wqkv_v_t, bqkv_v,
      vq_w, vk_w, vv_w, nullptr, 0, 8192, NQKV, DIM);
  gemm128p<1><<<dim3(48,2), dim3(256), 0, stream>>>(txt_bf, Wqkv_t_t, bqkv_t,
      tq_w, tk_w, tv_w, nullptr, 0, 256, NQKV, DIM);

  // V transpose (after QKV gemms; vvT aliases vid_bf which is now dead)
  vtrans_kernel<<<dim3(512,4), dim3(256), 0, stream>>>(vv_w, vvT);
  vtrans_kernel<<<dim3(16,4),  dim3(256), 0, stream>>>(tv_w, tvT);

  // RMSNorm for K only (Q fused into attention)
  rms_kernel<<<dim3(32768), dim3(256), 0, stream>>>(vk_w, gk_v, 32*16*256);
  rms_kernel<<<dim3(1024),  dim3(256), 0, stream>>>(tk_w, gk_t, 16*256);

  // attention (2048 blocks, XCD-chunked; text rows -> per-window bf16 partials)
  attn_kernel<<<dim3(2048), dim3(512), 0, stream>>>(vq_w, vk_w, vvT, tq_w, tk_w, tvT,
                                                    gq_v, gq_t, vo_pre, to_part);

  // reduce text partials over windows -> to_bf
  reduce_txt<<<dim3(256), dim3(256), 0, stream>>>(to_part, to_bf);

  // output projections
  gemm256<2><<<dim3(8,32), dim3(512), 0, stream>>>(vo_pre, Wo_v_t, bo_v,
      nullptr, nullptr, nullptr, out, 2048, 8192, 2048, 2048);
  gemm128p<2><<<dim3(16,2), dim3(256), 0, stream>>>(to_bf, Wo_t_t, bo_t,
      nullptr, nullptr, nullptr, out + 16777216, 2048, 256, 2048, 2048);
}

// Round 11
// 607.473 us; speedup vs baseline: 1.0606x; 1.0011x over previous
//
#include <hip/hip_runtime.h>

typedef unsigned short u16;
typedef unsigned int   u32;
typedef __attribute__((ext_vector_type(8))) short short8;   // 8 x bf16 (4 VGPRs)
typedef __attribute__((ext_vector_type(4))) float f32x4;    // MFMA accum

// ---------------- helpers ----------------
__device__ __forceinline__ u16 f2bf(float f) {
  union { float f; u32 u; } v; v.f = f;
  u32 r = v.u + 0x7fffu + ((v.u >> 16) & 1u);   // RNE
  return (u16)(r >> 16);
}
__device__ __forceinline__ float bf2f(u32 bits) {
  union { u32 u; float f; } v; v.u = bits << 16; return v.f;
}
// async global->LDS, 16B per lane. LDS dest is WAVE-UNIFORM base; HW adds lane*16.
__device__ __forceinline__ void gl_lds16(const u16* g, u16* l) {
  __builtin_amdgcn_global_load_lds(
      (const __attribute__((address_space(1))) void*)g,
      (__attribute__((address_space(3))) void*)l, 16, 0, 0);
}

// ---------------- problem constants ----------------
static constexpr int DIM  = 2048;
static constexpr int NQKV = 6144;

// ---------------- merged f32 -> bf16 convert (vid + txt in one launch) --------------
__global__ __launch_bounds__(256) void conv_all(const float* __restrict__ vid,
                                                u16* __restrict__ vid_bf,
                                                const float* __restrict__ txt,
                                                u16* __restrict__ txt_bf) {
  const int N4V = 8192*2048/4;
  const int N4T = 256*2048/4;
  int id = blockIdx.x * 256 + threadIdx.x;
  const float* in; u16* out; int i;
  if (id < N4V) { in = vid; out = vid_bf; i = id; }
  else { i = id - N4V; if (i >= N4T) return; in = txt; out = txt_bf; }
  float4 v = ((const float4*)in)[i];
  u32 lo = (u32)f2bf(v.x) | ((u32)f2bf(v.y) << 16);
  u32 hi = (u32)f2bf(v.z) | ((u32)f2bf(v.w) << 16);
  ((uint2*)out)[i] = make_uint2(lo, hi);
}

// ------- merged transpose+convert for all 4 weights: W[K][N] f32 -> Wt[N][K] bf16 ----
__global__ void tconv_all(const float* __restrict__ W0, u16* __restrict__ D0,
                          const float* __restrict__ W1, u16* __restrict__ D1,
                          const float* __restrict__ W2, u16* __restrict__ D2,
                          const float* __restrict__ W3, u16* __restrict__ D3) {
  __shared__ float t[32][33];
  const int K = 2048;
  int bid = blockIdx.x;
  const float* W; u16* Wt; int N, lb;
  if      (bid < 12288) { W = W0; Wt = D0; N = 6144; lb = bid; }
  else if (bid < 24576) { W = W1; Wt = D1; N = 6144; lb = bid - 12288; }
  else if (bid < 28672) { W = W2; Wt = D2; N = 2048; lb = bid - 24576; }
  else                  { W = W3; Wt = D3; N = 2048; lb = bid - 28672; }
  int nbx = N >> 5;
  int n0 = (lb % nbx) * 32, k0 = (lb / nbx) * 32;
  int tx = threadIdx.x, ty = threadIdx.y;           // 32 x 8
  #pragma unroll
  for (int i = 0; i < 4; ++i)
    t[ty + i*8][tx] = W[(size_t)(k0 + ty + i*8) * N + n0 + tx];
  __syncthreads();
  #pragma unroll
  for (int i = 0; i < 4; ++i)
    Wt[(size_t)(n0 + ty + i*8) * K + k0 + tx] = f2bf(t[tx][ty + i*8]);
}

// -------- merged RMSNorm in-place (vk_w rows then tk_w rows), 1 wave / row ----------
__global__ __launch_bounds__(256) void rms_all(u16* __restrict__ xv, const float* __restrict__ gv,
                                               u16* __restrict__ xt, const float* __restrict__ gt) {
  const int NRV = 32*16*256;                         // 131072
  int w = threadIdx.x >> 6, lane = threadIdx.x & 63;
  int rid = blockIdx.x * 4 + w;
  u32* row; const float* g;
  if (rid < NRV) { row = (u32*)xv + (size_t)rid * 64; g = gv; }
  else {
    int r2 = rid - NRV; if (r2 >= 16*256) return;
    row = (u32*)xt + (size_t)r2 * 64; g = gt;
  }
  u32 u = row[lane];
  float f0 = bf2f(u & 0xffffu), f1 = bf2f(u >> 16);
  float s = f0*f0 + f1*f1;
  #pragma unroll
  for (int off = 1; off <= 32; off <<= 1) s += __shfl_xor(s, off);
  float r = rsqrtf(s * (1.0f/128.0f) + 1e-6f);
  float g0 = g[lane*2], g1 = g[lane*2+1];
  row[lane] = (u32)f2bf(f0*r*g0) | ((u32)f2bf(f1*r*g1) << 16);
}

// ------- merged V transpose: [nh][256 key][128 d] -> [nh][128 d][256 key] -----------
// nh < 512: vv_w; else tv_w. Dest is contiguous (tvT = vvT + 512*128*256).
__global__ __launch_bounds__(256)
void vtrans_all(const u16* __restrict__ vv_w, const u16* __restrict__ tv_w,
                u16* __restrict__ vvT) {
  __shared__ u16 t[64][130];
  int nh = blockIdx.x, k0 = blockIdx.y * 64;
  const u16* s = (nh < 512) ? (vv_w + ((size_t)nh*256 + k0)*128)
                            : (tv_w + ((size_t)(nh-512)*256 + k0)*128);
  u16* d = vvT + (size_t)nh*128*256 + k0;
  int tid = threadIdx.x;
  #pragma unroll
  for (int it = 0; it < 4; ++it) {
    int c = tid + it*256;
    int row = c >> 4, ch = c & 15;
    short8 v = *(const short8*)(s + row*128 + ch*8);
    u32* dst32 = (u32*)&t[row][ch*8];
    const u32* v32 = (const u32*)&v;
    dst32[0] = v32[0]; dst32[1] = v32[1]; dst32[2] = v32[2]; dst32[3] = v32[3];
  }
  __syncthreads();
  #pragma unroll
  for (int it = 0; it < 4; ++it) {
    int c = tid + it*256;
    int dr = c >> 3, kg = c & 7;
    short8 v;
    #pragma unroll
    for (int j = 0; j < 8; ++j) v[j] = (short)t[kg*8+j][dr];
    *(short8*)(d + (size_t)dr*256 + kg*8) = v;
  }
}

// ---------------- text-output reduction: mean over 32 windows of bf16 partials ------
__global__ __launch_bounds__(256)
void reduce_txt(const u16* __restrict__ part, u16* __restrict__ to_bf) {
  int row = blockIdx.x, c8 = threadIdx.x;
  const u16* p = part + (size_t)row*2048 + c8*8;
  float s[8] = {};
  #pragma unroll 4
  for (int wn = 0; wn < 32; ++wn) {
    short8 v = *(const short8*)(p + (size_t)wn*256*2048);
    #pragma unroll
    for (int j = 0; j < 8; ++j) s[j] += bf2f((u16)v[j]);
  }
  short8 o;
  #pragma unroll
  for (int j = 0; j < 8; ++j) o[j] = (short)f2bf(s[j] * (1.0f/32.0f));
  *(short8*)(to_bf + (size_t)row*2048 + c8*8) = o;
}

// ============== 256x256-tile pipelined GEMM, BK=32, 4-buffer ring, 8 waves ==========
// (R6 known-good form: top-of-tile counted vmcnt + single barrier, 0 bank conflicts)
template<int EPI>
__global__ __launch_bounds__(512, 2)
void gemm256(const u16* __restrict__ A, const u16* __restrict__ Bt,
             const float* __restrict__ bias,
             u16* __restrict__ o0, u16* __restrict__ o1, u16* __restrict__ o2,
             float* __restrict__ of, int ldo, int M, int N, int K)
{
  __shared__ __align__(16) u16 As[4][256*32];
  __shared__ __align__(16) u16 Bs[4][256*32];
  const int NT = K >> 5;
  int tid = threadIdx.x, lane = tid & 63, w = tid >> 6;
  int l15 = lane & 15, l4 = lane >> 4;
  int wm = w >> 2, wn = w & 3;                   // 2M x 4N wave grid

  int nbx = gridDim.x;
  int nwg = nbx * gridDim.y;
  int bid = blockIdx.y * nbx + blockIdx.x;
  int cpx = nwg >> 3;
  int swz = (bid & 7) * cpx + (bid >> 3);
  int n0 = (swz % nbx) * 256, m0 = (swz / nbx) * 256;

  int srow = tid >> 2, skc = (tid & 3) ^ ((tid >> 3) & 3);
  const u16* aS = A  + (size_t)(m0 + srow) * K + skc * 8;
  const u16* bS = Bt + (size_t)(n0 + srow) * K + skc * 8;
  const size_t halfStride = 128 * (size_t)K;
  const int ldsBase = w * 512;

  #define STAGE_A(slot, tt, half) \
    gl_lds16(aS + (size_t)(tt)*32 + (half)*halfStride, &As[slot][(half)*4096 + ldsBase])
  #define STAGE_B(slot, tt, half) \
    gl_lds16(bS + (size_t)(tt)*32 + (half)*halfStride, &Bs[slot][(half)*4096 + ldsBase])

  #pragma unroll
  for (int pt = 0; pt < 3; ++pt) {
    STAGE_A(pt, pt, 0); STAGE_A(pt, pt, 1);
    STAGE_B(pt, pt, 0); STAGE_B(pt, pt, 1);
  }

  f32x4 acc[8][4] = {};

  for (int t = 0; t < NT; ++t) {
    if (t < NT - 2)       asm volatile("s_waitcnt vmcnt(8)" ::: "memory");
    else if (t == NT - 2) asm volatile("s_waitcnt vmcnt(4)" ::: "memory");
    else                  asm volatile("s_waitcnt vmcnt(0)" ::: "memory");
    __builtin_amdgcn_s_barrier();
    asm volatile("" ::: "memory");

    const u16* ab = As[t & 3];
    const u16* bb = Bs[t & 3];
    bool st = (t + 3 < NT);
    int slot = (t + 3) & 3;

    short8 bf_[4];
    #pragma unroll
    for (int j = 0; j < 4; ++j) {
      int rb = wn*64 + j*16 + l15;
      bf_[j] = *(const short8*)((const char*)bb + rb*64 + ((l4 ^ ((rb>>1)&3))*16));
    }

    short8 af[4];
    #pragma unroll
    for (int i = 0; i < 4; ++i) {
      int ra = wm*128 + i*16 + l15;
      af[i] = *(const short8*)((const char*)ab + ra*64 + ((l4 ^ ((ra>>1)&3))*16));
    }
    if (st) { STAGE_A(slot, t+3, 0); STAGE_A(slot, t+3, 1); }
    __builtin_amdgcn_s_setprio(1);
    #pragma unroll
    for (int i = 0; i < 4; ++i)
      #pragma unroll
      for (int j = 0; j < 4; ++j)
        acc[i][j] = __builtin_amdgcn_mfma_f32_16x16x32_bf16(af[i], bf_[j], acc[i][j], 0, 0, 0);
    __builtin_amdgcn_s_setprio(0);

    #pragma unroll
    for (int i = 0; i < 4; ++i) {
      int ra = wm*128 + 64 + i*16 + l15;
      af[i] = *(const short8*)((const char*)ab + ra*64 + ((l4 ^ ((ra>>1)&3))*16));
    }
    if (st) { STAGE_B(slot, t+3, 0); STAGE_B(slot, t+3, 1); }
    __builtin_amdgcn_s_setprio(1);
    #pragma unroll
    for (int i = 0; i < 4; ++i)
      #pragma unroll
      for (int j = 0; j < 4; ++j)
        acc[4+i][j] = __builtin_amdgcn_mfma_f32_16x16x32_bf16(af[i], bf_[j], acc[4+i][j], 0, 0, 0);
    __builtin_amdgcn_s_setprio(0);
  }
  #undef STAGE_A
  #undef STAGE_B

  #pragma unroll
  for (int i = 0; i < 8; ++i)
    #pragma unroll
    for (int j = 0; j < 4; ++j)
      #pragma unroll
      for (int r = 0; r < 4; ++r) {
        int m = m0 + wm*128 + i*16 + l4*4 + r;
        int n = n0 + wn*64  + j*16 + l15;
        float v = acc[i][j][r] + bias[n];
        if (EPI == 0) {           // vid QKV -> windowed [win][head][p][128]
          int which = n >> 11, head = (n >> 7) & 15, d = n & 127;
          int t = m >> 10, hh = (m >> 5) & 31, ww = m & 31;
          int win = ((t>>2)<<4) + ((hh>>3)<<2) + (ww>>3);
          int p   = ((t&3)<<6) + ((hh&7)<<3) + (ww&7);
          u16* dst = which == 0 ? o0 : (which == 1 ? o1 : o2);
          dst[((size_t)(win*16 + head)*256 + p)*128 + d] = f2bf(v);
        } else {                  // plain f32
          of[(size_t)m * ldo + n] = v;
        }
      }
}

// ======= 128x128-tile pipelined GEMM, BK=32, 4-slot ring, 4 waves (txt matrices) ====
template<int EPI>
__global__ __launch_bounds__(256, 2)
void gemm128p(const u16* __restrict__ A, const u16* __restrict__ Bt,
              const float* __restrict__ bias,
              u16* __restrict__ o0, u16* __restrict__ o1, u16* __restrict__ o2,
              float* __restrict__ of, int ldo, int M, int N, int K)
{
  __shared__ __align__(16) u16 As[4][128*32];
  __shared__ __align__(16) u16 Bs[4][128*32];
  const int NT = K >> 5;
  int tid = threadIdx.x, lane = tid & 63, w = tid >> 6;
  int l15 = lane & 15, l4 = lane >> 4;
  int m0 = blockIdx.y * 128, n0 = blockIdx.x * 128;
  int wr = (w >> 1) * 64, wc = (w & 1) * 64;

  int srow = tid >> 2, skc = (tid & 3) ^ ((tid >> 3) & 3);
  const u16* aS = A  + (size_t)(m0 + srow) * K + skc * 8;
  const u16* bS = Bt + (size_t)(n0 + srow) * K + skc * 8;
  const size_t halfStride = 64 * (size_t)K;
  const int ldsBase = w * 512;

  #define STAGE_A(slot, tt, half) \
    gl_lds16(aS + (size_t)(tt)*32 + (half)*halfStride, &As[slot][(half)*2048 + ldsBase])
  #define STAGE_B(slot, tt, half) \
    gl_lds16(bS + (size_t)(tt)*32 + (half)*halfStride, &Bs[slot][(half)*2048 + ldsBase])

  #pragma unroll
  for (int pt = 0; pt < 3; ++pt) {
    STAGE_A(pt, pt, 0); STAGE_A(pt, pt, 1);
    STAGE_B(pt, pt, 0); STAGE_B(pt, pt, 1);
  }

  f32x4 acc[4][4] = {};

  for (int t = 0; t < NT; ++t) {
    if (t < NT - 2)       asm volatile("s_waitcnt vmcnt(8)" ::: "memory");
    else if (t == NT - 2) asm volatile("s_waitcnt vmcnt(4)" ::: "memory");
    else                  asm volatile("s_waitcnt vmcnt(0)" ::: "memory");
    __builtin_amdgcn_s_barrier();
    asm volatile("" ::: "memory");

    const u16* ab = As[t & 3];
    const u16* bb = Bs[t & 3];
    bool st = (t + 3 < NT);
    int slot = (t + 3) & 3;

    short8 af[4], bfr[4];
    #pragma unroll
    for (int i = 0; i < 4; ++i) {
      int ra = wr + i*16 + l15;
      af[i]  = *(const short8*)((const char*)ab + ra*64 + ((l4 ^ ((ra>>1)&3))*16));
      int rb = wc + i*16 + l15;
      bfr[i] = *(const short8*)((const char*)bb + rb*64 + ((l4 ^ ((rb>>1)&3))*16));
    }
    if (st) {
      STAGE_A(slot, t+3, 0); STAGE_A(slot, t+3, 1);
      STAGE_B(slot, t+3, 0); STAGE_B(slot, t+3, 1);
    }
    __builtin_amdgcn_s_setprio(1);
    #pragma unroll
    for (int i = 0; i < 4; ++i)
      #pragma unroll
      for (int j = 0; j < 4; ++j)
        acc[i][j] = __builtin_amdgcn_mfma_f32_16x16x32_bf16(af[i], bfr[j], acc[i][j], 0, 0, 0);
    __builtin_amdgcn_s_setprio(0);
  }
  #undef STAGE_A
  #undef STAGE_B

  #pragma unroll
  for (int i = 0; i < 4; ++i)
    #pragma unroll
    for (int j = 0; j < 4; ++j)
      #pragma unroll
      for (int r = 0; r < 4; ++r) {
        int m = m0 + wr + i*16 + l4*4 + r;
        int n = n0 + wc + j*16 + l15;
        float v = acc[i][j][r] + bias[n];
        if (EPI == 1) {           // txt QKV -> [head][p][128]
          int which = n >> 11, head = (n >> 7) & 15, d = n & 127;
          u16* dst = which == 0 ? o0 : (which == 1 ? o1 : o2);
          dst[((size_t)head*256 + m)*128 + d] = f2bf(v);
        } else {                  // plain f32
          of[(size_t)m * ldo + n] = v;
        }
      }
}

// ---------------- fused windowed attention: exp2-domain softmax + defer-max ---------
// 2048 blocks, XCD-chunked. 8 waves x 16 q-rows. K/V double-buffered (64 KB),
// P written into dead K-buffer. Text rows -> per-window bf16 partials.
__global__ __launch_bounds__(512, 4)
void attn_kernel(const u16* __restrict__ vq, const u16* __restrict__ vk, const u16* __restrict__ vv,
                 const u16* __restrict__ tq, const u16* __restrict__ tk, const u16* __restrict__ tv,
                 const float* __restrict__ gq_v, const float* __restrict__ gq_t,
                 u16* __restrict__ vo, u16* __restrict__ to_part)
{
  __shared__ __align__(16) u16 Ks[2*64*128];    // [buf][key][d] swizzled; cur reused for P
  __shared__ __align__(16) u16 Vt[2*128*64];    // [buf][d][key] swizzled
  int tid = threadIdx.x, lane = tid & 63, w = tid >> 6;
  int l15 = lane & 15, l4 = lane >> 4;
  int bid = blockIdx.x;
  int logical = (bid & 7) * 256 + (bid >> 3);
  int nh_ = logical >> 2, qq = logical & 3;
  int h = nh_ & 15;
  int n = nh_ >> 4;
  int qt = qq * 128 + w * 16;

  // ---- Q load + fused RMSNorm ----
  const u16* Qb; const float* gq;
  if (qt < 256) { Qb = vq + ((size_t)nh_*256 + qt)*128; gq = gq_v; }
  else          { Qb = tq + ((size_t)h  *256 + (qt-256))*128; gq = gq_t; }
  short8 qf[4];
  float qv[4][8];
  float ss = 0.f;
  #pragma unroll
  for (int dt = 0; dt < 4; ++dt) {
    qf[dt] = *(const short8*)(Qb + l15*128 + l4*8 + dt*32);
    #pragma unroll
    for (int j = 0; j < 8; ++j) {
      float f = bf2f((u16)qf[dt][j]);
      qv[dt][j] = f; ss += f*f;
    }
  }
  ss += __shfl_xor(ss, 16); ss += __shfl_xor(ss, 32);
  float rr = rsqrtf(ss * (1.0f/128.0f) + 1e-6f);
  #pragma unroll
  for (int dt = 0; dt < 4; ++dt) {
    float4 g0 = *(const float4*)(gq + l4*8 + dt*32);
    float4 g1 = *(const float4*)(gq + l4*8 + dt*32 + 4);
    qf[dt][0] = (short)f2bf(qv[dt][0]*rr*g0.x); qf[dt][1] = (short)f2bf(qv[dt][1]*rr*g0.y);
    qf[dt][2] = (short)f2bf(qv[dt][2]*rr*g0.z); qf[dt][3] = (short)f2bf(qv[dt][3]*rr*g0.w);
    qf[dt][4] = (short)f2bf(qv[dt][4]*rr*g1.x); qf[dt][5] = (short)f2bf(qv[dt][5]*rr*g1.y);
    qf[dt][6] = (short)f2bf(qv[dt][6]*rr*g1.z); qf[dt][7] = (short)f2bf(qv[dt][7]*rr*g1.w);
  }

  // ---- staging geometry ----
  int oK0 = w*1024 + lane*16, oK1 = oK0 + 8192;
  int kr0 = oK0 >> 8, kc0 = ((oK0 >> 4) & 15) ^ (kr0 & 7);
  int kr1 = oK1 >> 8, kc1 = ((oK1 >> 4) & 15) ^ (kr1 & 7);
  int vd0 = oK0 >> 7, vc0 = ((oK0 >> 4) & 7) ^ (vd0 & 7);
  int vd1 = oK1 >> 7, vc1 = ((oK1 >> 4) & 7) ^ (vd1 & 7);

  f32x4 o_[8] = {};
  float m_run[4] = {-1e30f,-1e30f,-1e30f,-1e30f};
  float l_run[4] = {0.f,0.f,0.f,0.f};
  // softmax in exp2 domain: scale2 = (1/sqrt(128)) * log2(e)
  const float scale2 = 0.08838834764831845f * 1.4426950408889634f;
  const float THR2 = 11.5f;                      // defer-max threshold (~8 nats)

  #define STAGE_CHUNK(cc, buf)                                                        \
    {                                                                                 \
      int kb = (cc) * 64;                                                             \
      const u16* Kc; const u16* Vb; int vkb;                                          \
      if (kb < 256) { Kc = vk + ((size_t)nh_*256 + kb)*128;                           \
                      Vb = vv + (size_t)nh_*128*256; vkb = kb; }                      \
      else          { Kc = tk + ((size_t)h*256 + (kb-256))*128;                       \
                      Vb = tv + (size_t)h*128*256; vkb = kb - 256; }                  \
      gl_lds16(Kc + kr0*128 + kc0*8, Ks + (buf)*8192 + w*512);                        \
      gl_lds16(Kc + kr1*128 + kc1*8, Ks + (buf)*8192 + w*512 + 4096);                 \
      gl_lds16(Vb + (size_t)vd0*256 + vkb + vc0*8, Vt + (buf)*8192 + w*512);          \
      gl_lds16(Vb + (size_t)vd1*256 + vkb + vc1*8, Vt + (buf)*8192 + w*512 + 4096);   \
    }

  STAGE_CHUNK(0, 0);

  for (int c = 0; c < 8; ++c) {
    int cur = c & 1;
    __builtin_amdgcn_s_barrier();          // A: prev chunk's readers of ^cur done
    if (c < 7) STAGE_CHUNK(c + 1, cur ^ 1);
    if (c < 7) asm volatile("s_waitcnt vmcnt(4)" ::: "memory");
    else       asm volatile("s_waitcnt vmcnt(0)" ::: "memory");
    __builtin_amdgcn_s_barrier();          // B0: all waves' chunk-c loads visible
    const char* KsB = (const char*)(Ks + cur*8192);
    const char* VtB = (const char*)(Vt + cur*8192);

    // ---- S = Q K^T ----
    f32x4 s4[4];
    __builtin_amdgcn_s_setprio(1);
    #pragma unroll
    for (int kt = 0; kt < 4; ++kt) {
      f32x4 sa = {0.f,0.f,0.f,0.f};
      int key = kt*16 + l15;
      #pragma unroll
      for (int dt = 0; dt < 4; ++dt) {
        int c16b = l4 + dt*4;
        short8 kf = *(const short8*)(KsB + key*256 + (((c16b ^ (key&7)))*16));
        sa = __builtin_amdgcn_mfma_f32_16x16x32_bf16(qf[dt], kf, sa, 0, 0, 0);
      }
      s4[kt] = sa;
    }
    __builtin_amdgcn_s_setprio(0);

    // ---- online softmax (exp2 domain, defer-max) ----
    float mx[4];
    #pragma unroll
    for (int r = 0; r < 4; ++r) {
      float m4 = fmaxf(fmaxf(s4[0][r], s4[1][r]), fmaxf(s4[2][r], s4[3][r])) * scale2;
      #pragma unroll
      for (int off = 1; off <= 8; off <<= 1) m4 = fmaxf(m4, __shfl_xor(m4, off));
      mx[r] = m4;
    }
    bool grow = (mx[0] > m_run[0] + THR2) | (mx[1] > m_run[1] + THR2) |
                (mx[2] > m_run[2] + THR2) | (mx[3] > m_run[3] + THR2);
    if (__ballot(grow)) {                   // per-wave uniform rescale path
      #pragma unroll
      for (int r = 0; r < 4; ++r) {
        float nm = fmaxf(m_run[r], mx[r]);
        float f_ = exp2f(m_run[r] - nm);
        m_run[r] = nm;
        l_run[r] *= f_;
        #pragma unroll
        for (int dt = 0; dt < 8; ++dt) o_[dt][r] *= f_;
      }
    }
    float p[4][4];
    #pragma unroll
    for (int kt = 0; kt < 4; ++kt)
      #pragma unroll
      for (int r = 0; r < 4; ++r)
        p[kt][r] = exp2f(s4[kt][r]*scale2 - m_run[r]);
    #pragma unroll
    for (int r = 0; r < 4; ++r) {
      float sum = p[0][r] + p[1][r] + p[2][r] + p[3][r];
      #pragma unroll
      for (int off = 1; off <= 8; off <<= 1) sum += __shfl_xor(sum, off);
      l_run[r] += sum;
    }

    __builtin_amdgcn_s_barrier();          // B1: all QK reads of Ks[cur] done
    // ---- P -> dead Ks[cur] (wave-private region, XOR chunk^(q&7)) ----
    u16* pw = Ks + cur*8192 + w*1024;
    #pragma unroll
    for (int kt = 0; kt < 4; ++kt)
      #pragma unroll
      for (int r = 0; r < 4; ++r) {
        int q = l4*4 + r;
        pw[q*64 + (((kt*2 + (l15>>3)) ^ (q&7))<<3) + (l15&7)] = f2bf(p[kt][r]);
      }
    // ---- PV ----
    #pragma unroll
    for (int ks = 0; ks < 2; ++ks) {
      short8 pa = *(const short8*)((const char*)pw + l15*128 + (((ks*4 + l4) ^ (l15&7))<<4));
      __builtin_amdgcn_s_setprio(1);
      #pragma unroll
      for (int dt = 0; dt < 8; ++dt) {
        int d = dt*16 + l15;
        short8 vf = *(const short8*)(VtB + d*128 + (((ks*4 + l4) ^ (d&7))<<4));
        o_[dt] = __builtin_amdgcn_mfma_f32_16x16x32_bf16(pa, vf, o_[dt], 0, 0, 0);
      }
      __builtin_amdgcn_s_setprio(0);
    }
  }
  #undef STAGE_CHUNK

  // ---- epilogue ----
  float inv[4];
  #pragma unroll
  for (int r = 0; r < 4; ++r) inv[r] = 1.0f / l_run[r];
  int nt = n >> 4, nh2 = (n >> 2) & 3, nw = n & 3;
  #pragma unroll
  for (int dt = 0; dt < 8; ++dt) {
    int d = dt*16 + l15;
    int col = h*128 + d;
    #pragma unroll
    for (int r = 0; r < 4; ++r) {
      float val = o_[dt][r] * inv[r];
      int q = qt + l4*4 + r;
      if (q < 256) {
        int wt = q >> 6, wh = (q >> 3) & 7, ww = q & 7;
        int rg = ((nt*4 + wt)*32 + (nh2*8 + wh))*32 + (nw*8 + ww);
        vo[(size_t)rg*2048 + col] = f2bf(val);
      } else {
        to_part[((size_t)n*256 + (q - 256))*2048 + col] = f2bf(val);
      }
    }
  }
}

// ---------------- host launch ----------------
extern "C" void kernel_launch(void* const* d_in, const int* in_sizes, int n_in,
                              void* d_out, int out_size, void* d_ws, size_t ws_size,
                              hipStream_t stream) {
  const float* vid    = (const float*)d_in[0];
  const float* txt    = (const float*)d_in[1];
  const float* Wqkv_v = (const float*)d_in[2];
  const float* bqkv_v = (const float*)d_in[3];
  const float* Wqkv_t = (const float*)d_in[4];
  const float* bqkv_t = (const float*)d_in[5];
  const float* Wo_v   = (const float*)d_in[6];
  const float* bo_v   = (const float*)d_in[7];
  const float* Wo_t   = (const float*)d_in[8];
  const float* bo_t   = (const float*)d_in[9];
  const float* gq_v   = (const float*)d_in[10];
  const float* gk_v   = (const float*)d_in[11];
  const float* gq_t   = (const float*)d_in[12];
  const float* gk_t   = (const float*)d_in[13];
  float* out = (float*)d_out;

  char* p = (char*)d_ws;
  u16* vid_bf   = (u16*)p;  p += 8192ull*2048*2;
  u16* txt_bf   = (u16*)p;  p += 256ull*2048*2;
  u16* Wqkv_v_t = (u16*)p;  p += 6144ull*2048*2;
  u16* Wqkv_t_t = (u16*)p;  p += 6144ull*2048*2;
  u16* Wo_v_t   = (u16*)p;  p += 2048ull*2048*2;
  u16* Wo_t_t   = (u16*)p;  p += 2048ull*2048*2;
  u16* vq_w     = (u16*)p;  p += 32ull*16*256*128*2;
  u16* vk_w     = (u16*)p;  p += 32ull*16*256*128*2;
  u16* vv_w     = (u16*)p;  p += 32ull*16*256*128*2;   // [win][head][key][d]
  u16* tq_w     = (u16*)p;  p += 16ull*256*128*2;
  u16* tk_w     = (u16*)p;  p += 16ull*256*128*2;
  u16* tv_w     = (u16*)p;  p += 16ull*256*128*2;      // [head][key][d]
  u16* vo_pre   = (u16*)p;  p += 8192ull*2048*2;
  float* to_pre = (float*)p; p += 256ull*2048*4;       // (unused)
  u16* to_bf    = (u16*)p;  p += 256ull*2048*2;
  // vvT/tvT alias vid_bf (dead after QKV gemms); tvT contiguous after vvT
  u16* vvT = vid_bf;                                    // [512 nh][128 d][256 key]
  // to_part aliases Wqkv_v_t (dead after QKV gemms): 32x256x2048 bf16 = 33.6 MB
  u16* to_part = Wqkv_v_t;
  (void)to_pre;

  // converts (merged)
  conv_all<<<dim3(16896), dim3(256), 0, stream>>>(vid, vid_bf, txt, txt_bf);
  tconv_all<<<dim3(32768), dim3(32,8), 0, stream>>>(Wqkv_v, Wqkv_v_t, Wqkv_t, Wqkv_t_t,
                                                    Wo_v, Wo_v_t, Wo_t, Wo_t_t);

  // QKV projections
  gemm256<0><<<dim3(24,32), dim3(512), 0, stream>>>(vid_bf, Wqkv_v_t, bqkv_v,
      vq_w, vk_w, vv_w, nullptr, 0, 8192, NQKV, DIM);
  gemm128p<1><<<dim3(48,2), dim3(256), 0, stream>>>(txt_bf, Wqkv_t_t, bqkv_t,
      tq_w, tk_w, tv_w, nullptr, 0, 256, NQKV, DIM);

  // V transpose (merged; vvT aliases vid_bf which is now dead)
  vtrans_all<<<dim3(528,4), dim3(256), 0, stream>>>(vv_w, tv_w, vvT);

  // K RMSNorm (merged; Q fused into attention)
  rms_all<<<dim3(33793), dim3(256), 0, stream>>>(vk_w, gk_v, tk_w, gk_t);

  // attention (2048 blocks, XCD-chunked; text rows -> per-window bf16 partials)
  attn_kernel<<<dim3(2048), dim3(512), 0, stream>>>(vq_w, vk_w, vvT, tq_w, tk_w,
                                                    vvT + 512ull*128*256,
                                                    gq_v, gq_t, vo_pre, to_part);

  // reduce text partials over windows -> to_bf
  reduce_txt<<<dim3(256), dim3(256), 0, stream>>>(to_part, to_bf);

  // output projections
  gemm256<2><<<dim3(8,32), dim3(512), 0, stream>>>(vo_pre, Wo_v_t, bo_v,
      nullptr, nullptr, nullptr, out, 2048, 8192, 2048, 2048);
  gemm128p<2><<<dim3(16,2), dim3(256), 0, stream>>>(to_bf, Wo_t_t, bo_t,
      nullptr, nullptr, nullptr, out + 16777216, 2048, 256, 2048, 2048);
}

// Round 13
// 605.395 us; speedup vs baseline: 1.0642x; 1.0034x over previous
//
#include <hip/hip_runtime.h>

typedef unsigned short u16;
typedef unsigned int   u32;
typedef __attribute__((ext_vector_type(8))) short short8;   // 8 x bf16 (4 VGPRs)
typedef __attribute__((ext_vector_type(4))) float f32x4;    // MFMA accum

// ---------------- helpers ----------------
__device__ __forceinline__ u16 f2bf(float f) {
  union { float f; u32 u; } v; v.f = f;
  u32 r = v.u + 0x7fffu + ((v.u >> 16) & 1u);   // RNE
  return (u16)(r >> 16);
}
__device__ __forceinline__ float bf2f(u32 bits) {
  union { u32 u; float f; } v; v.u = bits << 16; return v.f;
}
// async global->LDS, 16B per lane. LDS dest is WAVE-UNIFORM base; HW adds lane*16.
__device__ __forceinline__ void gl_lds16(const u16* g, u16* l) {
  __builtin_amdgcn_global_load_lds(
      (const __attribute__((address_space(1))) void*)g,
      (__attribute__((address_space(3))) void*)l, 16, 0, 0);
}

// ---------------- problem constants ----------------
static constexpr int DIM  = 2048;
static constexpr int NQKV = 6144;

// ---------------- merged f32 -> bf16 convert (vid + txt in one launch) --------------
__global__ __launch_bounds__(256) void conv_all(const float* __restrict__ vid,
                                                u16* __restrict__ vid_bf,
                                                const float* __restrict__ txt,
                                                u16* __restrict__ txt_bf) {
  const int N4V = 8192*2048/4;
  const int N4T = 256*2048/4;
  int id = blockIdx.x * 256 + threadIdx.x;
  const float* in; u16* out; int i;
  if (id < N4V) { in = vid; out = vid_bf; i = id; }
  else { i = id - N4V; if (i >= N4T) return; in = txt; out = txt_bf; }
  float4 v = ((const float4*)in)[i];
  u32 lo = (u32)f2bf(v.x) | ((u32)f2bf(v.y) << 16);
  u32 hi = (u32)f2bf(v.z) | ((u32)f2bf(v.w) << 16);
  ((uint2*)out)[i] = make_uint2(lo, hi);
}

// ------- merged transpose+convert for all 4 weights: W[K][N] f32 -> Wt[N][K] bf16 ----
__global__ void tconv_all(const float* __restrict__ W0, u16* __restrict__ D0,
                          const float* __restrict__ W1, u16* __restrict__ D1,
                          const float* __restrict__ W2, u16* __restrict__ D2,
                          const float* __restrict__ W3, u16* __restrict__ D3) {
  __shared__ float t[32][33];
  const int K = 2048;
  int bid = blockIdx.x;
  const float* W; u16* Wt; int N, lb;
  if      (bid < 12288) { W = W0; Wt = D0; N = 6144; lb = bid; }
  else if (bid < 24576) { W = W1; Wt = D1; N = 6144; lb = bid - 12288; }
  else if (bid < 28672) { W = W2; Wt = D2; N = 2048; lb = bid - 24576; }
  else                  { W = W3; Wt = D3; N = 2048; lb = bid - 28672; }
  int nbx = N >> 5;
  int n0 = (lb % nbx) * 32, k0 = (lb / nbx) * 32;
  int tx = threadIdx.x, ty = threadIdx.y;           // 32 x 8
  #pragma unroll
  for (int i = 0; i < 4; ++i)
    t[ty + i*8][tx] = W[(size_t)(k0 + ty + i*8) * N + n0 + tx];
  __syncthreads();
  #pragma unroll
  for (int i = 0; i < 4; ++i)
    Wt[(size_t)(n0 + ty + i*8) * K + k0 + tx] = f2bf(t[tx][ty + i*8]);
}

// -------- merged RMSNorm in-place (vk_w rows then tk_w rows), 1 wave / row ----------
__global__ __launch_bounds__(256) void rms_all(u16* __restrict__ xv, const float* __restrict__ gv,
                                               u16* __restrict__ xt, const float* __restrict__ gt) {
  const int NRV = 32*16*256;                         // 131072
  int w = threadIdx.x >> 6, lane = threadIdx.x & 63;
  int rid = blockIdx.x * 4 + w;
  u32* row; const float* g;
  if (rid < NRV) { row = (u32*)xv + (size_t)rid * 64; g = gv; }
  else {
    int r2 = rid - NRV; if (r2 >= 16*256) return;
    row = (u32*)xt + (size_t)r2 * 64; g = gt;
  }
  u32 u = row[lane];
  float f0 = bf2f(u & 0xffffu), f1 = bf2f(u >> 16);
  float s = f0*f0 + f1*f1;
  #pragma unroll
  for (int off = 1; off <= 32; off <<= 1) s += __shfl_xor(s, off);
  float r = rsqrtf(s * (1.0f/128.0f) + 1e-6f);
  float g0 = g[lane*2], g1 = g[lane*2+1];
  row[lane] = (u32)f2bf(f0*r*g0) | ((u32)f2bf(f1*r*g1) << 16);
}

// ------- merged V transpose: [nh][256 key][128 d] -> [nh][128 d][256 key] -----------
// nh < 512: vv_w; else tv_w. Dest is contiguous (tvT = vvT + 512*128*256).
__global__ __launch_bounds__(256)
void vtrans_all(const u16* __restrict__ vv_w, const u16* __restrict__ tv_w,
                u16* __restrict__ vvT) {
  __shared__ u16 t[64][130];
  int nh = blockIdx.x, k0 = blockIdx.y * 64;
  const u16* s = (nh < 512) ? (vv_w + ((size_t)nh*256 + k0)*128)
                            : (tv_w + ((size_t)(nh-512)*256 + k0)*128);
  u16* d = vvT + (size_t)nh*128*256 + k0;
  int tid = threadIdx.x;
  #pragma unroll
  for (int it = 0; it < 4; ++it) {
    int c = tid + it*256;
    int row = c >> 4, ch = c & 15;
    short8 v = *(const short8*)(s + row*128 + ch*8);
    u32* dst32 = (u32*)&t[row][ch*8];
    const u32* v32 = (const u32*)&v;
    dst32[0] = v32[0]; dst32[1] = v32[1]; dst32[2] = v32[2]; dst32[3] = v32[3];
  }
  __syncthreads();
  #pragma unroll
  for (int it = 0; it < 4; ++it) {
    int c = tid + it*256;
    int dr = c >> 3, kg = c & 7;
    short8 v;
    #pragma unroll
    for (int j = 0; j < 8; ++j) v[j] = (short)t[kg*8+j][dr];
    *(short8*)(d + (size_t)dr*256 + kg*8) = v;
  }
}

// ---------------- text-output reduction: mean over 32 windows of bf16 partials ------
__global__ __launch_bounds__(256)
void reduce_txt(const u16* __restrict__ part, u16* __restrict__ to_bf) {
  int row = blockIdx.x, c8 = threadIdx.x;
  const u16* p = part + (size_t)row*2048 + c8*8;
  float s[8] = {};
  #pragma unroll 4
  for (int wn = 0; wn < 32; ++wn) {
    short8 v = *(const short8*)(p + (size_t)wn*256*2048);
    #pragma unroll
    for (int j = 0; j < 8; ++j) s[j] += bf2f((u16)v[j]);
  }
  short8 o;
  #pragma unroll
  for (int j = 0; j < 8; ++j) o[j] = (short)f2bf(s[j] * (1.0f/32.0f));
  *(short8*)(to_bf + (size_t)row*2048 + c8*8) = o;
}

// ============== 256x256-tile pipelined GEMM, BK=32, 4-buffer ring, 8 waves ==========
// (R6 known-good form: top-of-tile counted vmcnt + single barrier, 0 bank conflicts)
template<int EPI>
__global__ __launch_bounds__(512, 2)
void gemm256(const u16* __restrict__ A, const u16* __restrict__ Bt,
             const float* __restrict__ bias,
             u16* __restrict__ o0, u16* __restrict__ o1, u16* __restrict__ o2,
             float* __restrict__ of, int ldo, int M, int N, int K)
{
  __shared__ __align__(16) u16 As[4][256*32];
  __shared__ __align__(16) u16 Bs[4][256*32];
  const int NT = K >> 5;
  int tid = threadIdx.x, lane = tid & 63, w = tid >> 6;
  int l15 = lane & 15, l4 = lane >> 4;
  int wm = w >> 2, wn = w & 3;                   // 2M x 4N wave grid

  int nbx = gridDim.x;
  int nwg = nbx * gridDim.y;
  int bid = blockIdx.y * nbx + blockIdx.x;
  int cpx = nwg >> 3;
  int swz = (bid & 7) * cpx + (bid >> 3);
  int n0 = (swz % nbx) * 256, m0 = (swz / nbx) * 256;

  int srow = tid >> 2, skc = (tid & 3) ^ ((tid >> 3) & 3);
  const u16* aS = A  + (size_t)(m0 + srow) * K + skc * 8;
  const u16* bS = Bt + (size_t)(n0 + srow) * K + skc * 8;
  const size_t halfStride = 128 * (size_t)K;
  const int ldsBase = w * 512;

  #define STAGE_A(slot, tt, half) \
    gl_lds16(aS + (size_t)(tt)*32 + (half)*halfStride, &As[slot][(half)*4096 + ldsBase])
  #define STAGE_B(slot, tt, half) \
    gl_lds16(bS + (size_t)(tt)*32 + (half)*halfStride, &Bs[slot][(half)*4096 + ldsBase])

  #pragma unroll
  for (int pt = 0; pt < 3; ++pt) {
    STAGE_A(pt, pt, 0); STAGE_A(pt, pt, 1);
    STAGE_B(pt, pt, 0); STAGE_B(pt, pt, 1);
  }

  f32x4 acc[8][4] = {};

  for (int t = 0; t < NT; ++t) {
    if (t < NT - 2)       asm volatile("s_waitcnt vmcnt(8)" ::: "memory");
    else if (t == NT - 2) asm volatile("s_waitcnt vmcnt(4)" ::: "memory");
    else                  asm volatile("s_waitcnt vmcnt(0)" ::: "memory");
    __builtin_amdgcn_s_barrier();
    asm volatile("" ::: "memory");

    const u16* ab = As[t & 3];
    const u16* bb = Bs[t & 3];
    bool st = (t + 3 < NT);
    int slot = (t + 3) & 3;

    short8 bf_[4];
    #pragma unroll
    for (int j = 0; j < 4; ++j) {
      int rb = wn*64 + j*16 + l15;
      bf_[j] = *(const short8*)((const char*)bb + rb*64 + ((l4 ^ ((rb>>1)&3))*16));
    }

    short8 af[4];
    #pragma unroll
    for (int i = 0; i < 4; ++i) {
      int ra = wm*128 + i*16 + l15;
      af[i] = *(const short8*)((const char*)ab + ra*64 + ((l4 ^ ((ra>>1)&3))*16));
    }
    if (st) { STAGE_A(slot, t+3, 0); STAGE_A(slot, t+3, 1); }
    __builtin_amdgcn_s_setprio(1);
    #pragma unroll
    for (int i = 0; i < 4; ++i)
      #pragma unroll
      for (int j = 0; j < 4; ++j)
        acc[i][j] = __builtin_amdgcn_mfma_f32_16x16x32_bf16(af[i], bf_[j], acc[i][j], 0, 0, 0);
    __builtin_amdgcn_s_setprio(0);

    #pragma unroll
    for (int i = 0; i < 4; ++i) {
      int ra = wm*128 + 64 + i*16 + l15;
      af[i] = *(const short8*)((const char*)ab + ra*64 + ((l4 ^ ((ra>>1)&3))*16));
    }
    if (st) { STAGE_B(slot, t+3, 0); STAGE_B(slot, t+3, 1); }
    __builtin_amdgcn_s_setprio(1);
    #pragma unroll
    for (int i = 0; i < 4; ++i)
      #pragma unroll
      for (int j = 0; j < 4; ++j)
        acc[4+i][j] = __builtin_amdgcn_mfma_f32_16x16x32_bf16(af[i], bf_[j], acc[4+i][j], 0, 0, 0);
    __builtin_amdgcn_s_setprio(0);
  }
  #undef STAGE_A
  #undef STAGE_B

  #pragma unroll
  for (int i = 0; i < 8; ++i)
    #pragma unroll
    for (int j = 0; j < 4; ++j)
      #pragma unroll
      for (int r = 0; r < 4; ++r) {
        int m = m0 + wm*128 + i*16 + l4*4 + r;
        int n = n0 + wn*64  + j*16 + l15;
        float v = acc[i][j][r] + bias[n];
        if (EPI == 0) {           // vid QKV -> windowed [win][head][p][128]
          int which = n >> 11, head = (n >> 7) & 15, d = n & 127;
          int t = m >> 10, hh = (m >> 5) & 31, ww = m & 31;
          int win = ((t>>2)<<4) + ((hh>>3)<<2) + (ww>>3);
          int p   = ((t&3)<<6) + ((hh&7)<<3) + (ww&7);
          u16* dst = which == 0 ? o0 : (which == 1 ? o1 : o2);
          dst[((size_t)(win*16 + head)*256 + p)*128 + d] = f2bf(v);
        } else {                  // plain f32
          of[(size_t)m * ldo + n] = v;
        }
      }
}

// ======= 128x128-tile pipelined GEMM, BK=32, 4-slot ring, 4 waves (txt matrices) ====
template<int EPI>
__global__ __launch_bounds__(256, 2)
void gemm128p(const u16* __restrict__ A, const u16* __restrict__ Bt,
              const float* __restrict__ bias,
              u16* __restrict__ o0, u16* __restrict__ o1, u16* __restrict__ o2,
              float* __restrict__ of, int ldo, int M, int N, int K)
{
  __shared__ __align__(16) u16 As[4][128*32];
  __shared__ __align__(16) u16 Bs[4][128*32];
  const int NT = K >> 5;
  int tid = threadIdx.x, lane = tid & 63, w = tid >> 6;
  int l15 = lane & 15, l4 = lane >> 4;
  int m0 = blockIdx.y * 128, n0 = blockIdx.x * 128;
  int wr = (w >> 1) * 64, wc = (w & 1) * 64;

  int srow = tid >> 2, skc = (tid & 3) ^ ((tid >> 3) & 3);
  const u16* aS = A  + (size_t)(m0 + srow) * K + skc * 8;
  const u16* bS = Bt + (size_t)(n0 + srow) * K + skc * 8;
  const size_t halfStride = 64 * (size_t)K;
  const int ldsBase = w * 512;                  // u16; wave covers 1KB per half

  #define STAGE_A(slot, tt, half) \
    gl_lds16(aS + (size_t)(tt)*32 + (half)*halfStride, &As[slot][(half)*2048 + ldsBase])
  #define STAGE_B(slot, tt, half) \
    gl_lds16(bS + (size_t)(tt)*32 + (half)*halfStride, &Bs[slot][(half)*2048 + ldsBase])

  #pragma unroll
  for (int pt = 0; pt < 3; ++pt) {
    STAGE_A(pt, pt, 0); STAGE_A(pt, pt, 1);
    STAGE_B(pt, pt, 0); STAGE_B(pt, pt, 1);
  }

  f32x4 acc[4][4] = {};

  for (int t = 0; t < NT; ++t) {
    if (t < NT - 2)       asm volatile("s_waitcnt vmcnt(8)" ::: "memory");
    else if (t == NT - 2) asm volatile("s_waitcnt vmcnt(4)" ::: "memory");
    else                  asm volatile("s_waitcnt vmcnt(0)" ::: "memory");
    __builtin_amdgcn_s_barrier();
    asm volatile("" ::: "memory");

    const u16* ab = As[t & 3];
    const u16* bb = Bs[t & 3];
    bool st = (t + 3 < NT);
    int slot = (t + 3) & 3;

    short8 af[4], bfr[4];
    #pragma unroll
    for (int i = 0; i < 4; ++i) {
      int ra = wr + i*16 + l15;
      af[i]  = *(const short8*)((const char*)ab + ra*64 + ((l4 ^ ((ra>>1)&3))*16));
      int rb = wc + i*16 + l15;
      bfr[i] = *(const short8*)((const char*)bb + rb*64 + ((l4 ^ ((rb>>1)&3))*16));
    }
    if (st) {
      STAGE_A(slot, t+3, 0); STAGE_A(slot, t+3, 1);
      STAGE_B(slot, t+3, 0); STAGE_B(slot, t+3, 1);
    }
    __builtin_amdgcn_s_setprio(1);
    #pragma unroll
    for (int i = 0; i < 4; ++i)
      #pragma unroll
      for (int j = 0; j < 4; ++j)
        acc[i][j] = __builtin_amdgcn_mfma_f32_16x16x32_bf16(af[i], bfr[j], acc[i][j], 0, 0, 0);
    __builtin_amdgcn_s_setprio(0);
  }
  #undef STAGE_A
  #undef STAGE_B

  #pragma unroll
  for (int i = 0; i < 4; ++i)
    #pragma unroll
    for (int j = 0; j < 4; ++j)
      #pragma unroll
      for (int r = 0; r < 4; ++r) {
        int m = m0 + wr + i*16 + l4*4 + r;
        int n = n0 + wc + j*16 + l15;
        float v = acc[i][j][r] + bias[n];
        if (EPI == 1) {           // txt QKV -> [head][p][128]
          int which = n >> 11, head = (n >> 7) & 15, d = n & 127;
          u16* dst = which == 0 ? o0 : (which == 1 ? o1 : o2);
          dst[((size_t)head*256 + m)*128 + d] = f2bf(v);
        } else {                  // plain f32
          of[(size_t)m * ldo + n] = v;
        }
      }
}

// ---------------- fused windowed attention: exp2-domain softmax + defer-max ---------
// 2048 blocks, XCD-chunked. 8 waves x 16 q-rows. K/V double-buffered (64 KB),
// P written into dead K-buffer. Text rows -> per-window bf16 partials.
__global__ __launch_bounds__(512, 4)
void attn_kernel(const u16* __restrict__ vq, const u16* __restrict__ vk, const u16* __restrict__ vv,
                 const u16* __restrict__ tq, const u16* __restrict__ tk, const u16* __restrict__ tv,
                 const float* __restrict__ gq_v, const float* __restrict__ gq_t,
                 u16* __restrict__ vo, u16* __restrict__ to_part)
{
  __shared__ __align__(16) u16 Ks[2*64*128];    // [buf][key][d] swizzled; cur reused for P
  __shared__ __align__(16) u16 Vt[2*128*64];    // [buf][d][key] swizzled
  int tid = threadIdx.x, lane = tid & 63, w = tid >> 6;
  int l15 = lane & 15, l4 = lane >> 4;
  int bid = blockIdx.x;
  int logical = (bid & 7) * 256 + (bid >> 3);
  int nh_ = logical >> 2, qq = logical & 3;
  int h = nh_ & 15;
  int n = nh_ >> 4;
  int qt = qq * 128 + w * 16;

  // ---- Q load + fused RMSNorm ----
  const u16* Qb; const float* gq;
  if (qt < 256) { Qb = vq + ((size_t)nh_*256 + qt)*128; gq = gq_v; }
  else          { Qb = tq + ((size_t)h  *256 + (qt-256))*128; gq = gq_t; }
  short8 qf[4];
  float qv[4][8];
  float ss = 0.f;
  #pragma unroll
  for (int dt = 0; dt < 4; ++dt) {
    qf[dt] = *(const short8*)(Qb + l15*128 + l4*8 + dt*32);
    #pragma unroll
    for (int j = 0; j < 8; ++j) {
      float f = bf2f((u16)qf[dt][j]);
      qv[dt][j] = f; ss += f*f;
    }
  }
  ss += __shfl_xor(ss, 16); ss += __shfl_xor(ss, 32);
  float rr = rsqrtf(ss * (1.0f/128.0f) + 1e-6f);
  #pragma unroll
  for (int dt = 0; dt < 4; ++dt) {
    float4 g0 = *(const float4*)(gq + l4*8 + dt*32);
    float4 g1 = *(const float4*)(gq + l4*8 + dt*32 + 4);
    qf[dt][0] = (short)f2bf(qv[dt][0]*rr*g0.x); qf[dt][1] = (short)f2bf(qv[dt][1]*rr*g0.y);
    qf[dt][2] = (short)f2bf(qv[dt][2]*rr*g0.z); qf[dt][3] = (short)f2bf(qv[dt][3]*rr*g0.w);
    qf[dt][4] = (short)f2bf(qv[dt][4]*rr*g1.x); qf[dt][5] = (short)f2bf(qv[dt][5]*rr*g1.y);
    qf[dt][6] = (short)f2bf(qv[dt][6]*rr*g1.z); qf[dt][7] = (short)f2bf(qv[dt][7]*rr*g1.w);
  }

  // ---- staging geometry ----
  int oK0 = w*1024 + lane*16, oK1 = oK0 + 8192;
  int kr0 = oK0 >> 8, kc0 = ((oK0 >> 4) & 15) ^ (kr0 & 7);
  int kr1 = oK1 >> 8, kc1 = ((oK1 >> 4) & 15) ^ (kr1 & 7);
  int vd0 = oK0 >> 7, vc0 = ((oK0 >> 4) & 7) ^ (vd0 & 7);
  int vd1 = oK1 >> 7, vc1 = ((oK1 >> 4) & 7) ^ (vd1 & 7);

  f32x4 o_[8] = {};
  float m_run[4] = {-1e30f,-1e30f,-1e30f,-1e30f};
  float l_run[4] = {0.f,0.f,0.f,0.f};
  // softmax in exp2 domain: scale2 = (1/sqrt(128)) * log2(e)
  const float scale2 = 0.08838834764831845f * 1.4426950408889634f;
  const float THR2 = 11.5f;                      // defer-max threshold (~8 nats)

  #define STAGE_CHUNK(cc, buf)                                                        \
    {                                                                                 \
      int kb = (cc) * 64;                                                             \
      const u16* Kc; const u16* Vb; int vkb;                                          \
      if (kb < 256) { Kc = vk + ((size_t)nh_*256 + kb)*128;                           \
                      Vb = vv + (size_t)nh_*128*256; vkb = kb; }                      \
      else          { Kc = tk + ((size_t)h*256 + (kb-256))*128;                       \
                      Vb = tv + (size_t)h*128*256; vkb = kb - 256; }                  \
      gl_lds16(Kc + kr0*128 + kc0*8, Ks + (buf)*8192 + w*512);                        \
      gl_lds16(Kc + kr1*128 + kc1*8, Ks + (buf)*8192 + w*512 + 4096);                 \
      gl_lds16(Vb + (size_t)vd0*256 + vkb + vc0*8, Vt + (buf)*8192 + w*512);          \
      gl_lds16(Vb + (size_t)vd1*256 + vkb + vc1*8, Vt + (buf)*8192 + w*512 + 4096);   \
    }

  STAGE_CHUNK(0, 0);

  for (int c = 0; c < 8; ++c) {
    int cur = c & 1;
    __builtin_amdgcn_s_barrier();          // A: prev chunk's readers of ^cur done
    if (c < 7) STAGE_CHUNK(c + 1, cur ^ 1);
    if (c < 7) asm volatile("s_waitcnt vmcnt(4)" ::: "memory");
    else       asm volatile("s_waitcnt vmcnt(0)" ::: "memory");
    __builtin_amdgcn_s_barrier();          // B0: all waves' chunk-c loads visible
    const char* KsB = (const char*)(Ks + cur*8192);
    const char* VtB = (const char*)(Vt + cur*8192);

    // ---- S = Q K^T ----
    f32x4 s4[4];
    __builtin_amdgcn_s_setprio(1);
    #pragma unroll
    for (int kt = 0; kt < 4; ++kt) {
      f32x4 sa = {0.f,0.f,0.f,0.f};
      int key = kt*16 + l15;
      #pragma unroll
      for (int dt = 0; dt < 4; ++dt) {
        int c16b = l4 + dt*4;
        short8 kf = *(const short8*)(KsB + key*256 + (((c16b ^ (key&7)))*16));
        sa = __builtin_amdgcn_mfma_f32_16x16x32_bf16(qf[dt], kf, sa, 0, 0, 0);
      }
      s4[kt] = sa;
    }
    __builtin_amdgcn_s_setprio(0);

    // ---- online softmax (exp2 domain, defer-max) ----
    float mx[4];
    #pragma unroll
    for (int r = 0; r < 4; ++r) {
      float m4 = fmaxf(fmaxf(s4[0][r], s4[1][r]), fmaxf(s4[2][r], s4[3][r])) * scale2;
      #pragma unroll
      for (int off = 1; off <= 8; off <<= 1) m4 = fmaxf(m4, __shfl_xor(m4, off));
      mx[r] = m4;
    }
    bool grow = (mx[0] > m_run[0] + THR2) | (mx[1] > m_run[1] + THR2) |
                (mx[2] > m_run[2] + THR2) | (mx[3] > m_run[3] + THR2);
    if (__ballot(grow)) {                   // per-wave uniform rescale path
      #pragma unroll
      for (int r = 0; r < 4; ++r) {
        float nm = fmaxf(m_run[r], mx[r]);
        float f_ = exp2f(m_run[r] - nm);
        m_run[r] = nm;
        l_run[r] *= f_;
        #pragma unroll
        for (int dt = 0; dt < 8; ++dt) o_[dt][r] *= f_;
      }
    }
    float p[4][4];
    #pragma unroll
    for (int kt = 0; kt < 4; ++kt)
      #pragma unroll
      for (int r = 0; r < 4; ++r)
        p[kt][r] = exp2f(s4[kt][r]*scale2 - m_run[r]);
    #pragma unroll
    for (int r = 0; r < 4; ++r) {
      float sum = p[0][r] + p[1][r] + p[2][r] + p[3][r];
      #pragma unroll
      for (int off = 1; off <= 8; off <<= 1) sum += __shfl_xor(sum, off);
      l_run[r] += sum;
    }

    __builtin_amdgcn_s_barrier();          // B1: all QK reads of Ks[cur] done
    // ---- P -> dead Ks[cur] (wave-private region, XOR chunk^(q&7)) ----
    u16* pw = Ks + cur*8192 + w*1024;
    #pragma unroll
    for (int kt = 0; kt < 4; ++kt)
      #pragma unroll
      for (int r = 0; r < 4; ++r) {
        int q = l4*4 + r;
        pw[q*64 + (((kt*2 + (l15>>3)) ^ (q&7))<<3) + (l15&7)] = f2bf(p[kt][r]);
      }
    // ---- PV ----
    #pragma unroll
    for (int ks = 0; ks < 2; ++ks) {
      short8 pa = *(const short8*)((const char*)pw + l15*128 + (((ks*4 + l4) ^ (l15&7))<<4));
      __builtin_amdgcn_s_setprio(1);
      #pragma unroll
      for (int dt = 0; dt < 8; ++dt) {
        int d = dt*16 + l15;
        short8 vf = *(const short8*)(VtB + d*128 + (((ks*4 + l4) ^ (d&7))<<4));
        o_[dt] = __builtin_amdgcn_mfma_f32_16x16x32_bf16(pa, vf, o_[dt], 0, 0, 0);
      }
      __builtin_amdgcn_s_setprio(0);
    }
  }
  #undef STAGE_CHUNK

  // ---- epilogue ----
  float inv[4];
  #pragma unroll
  for (int r = 0; r < 4; ++r) inv[r] = 1.0f / l_run[r];
  int nt = n >> 4, nh2 = (n >> 2) & 3, nw = n & 3;
  #pragma unroll
  for (int dt = 0; dt < 8; ++dt) {
    int d = dt*16 + l15;
    int col = h*128 + d;
    #pragma unroll
    for (int r = 0; r < 4; ++r) {
      float val = o_[dt][r] * inv[r];
      int q = qt + l4*4 + r;
      if (q < 256) {
        int wt = q >> 6, wh = (q >> 3) & 7, ww = q & 7;
        int rg = ((nt*4 + wt)*32 + (nh2*8 + wh))*32 + (nw*8 + ww);
        vo[(size_t)rg*2048 + col] = f2bf(val);
      } else {
        to_part[((size_t)n*256 + (q - 256))*2048 + col] = f2bf(val);
      }
    }
  }
}

// ---------------- host launch ----------------
extern "C" void kernel_launch(void* const* d_in, const int* in_sizes, int n_in,
                              void* d_out, int out_size, void* d_ws, size_t ws_size,
                              hipStream_t stream) {
  const float* vid    = (const float*)d_in[0];
  const float* txt    = (const float*)d_in[1];
  const float* Wqkv_v = (const float*)d_in[2];
  const float* bqkv_v = (const float*)d_in[3];
  const float* Wqkv_t = (const float*)d_in[4];
  const float* bqkv_t = (const float*)d_in[5];
  const float* Wo_v   = (const float*)d_in[6];
  const float* bo_v   = (const float*)d_in[7];
  const float* Wo_t   = (const float*)d_in[8];
  const float* bo_t   = (const float*)d_in[9];
  const float* gq_v   = (const float*)d_in[10];
  const float* gk_v   = (const float*)d_in[11];
  const float* gq_t   = (const float*)d_in[12];
  const float* gk_t   = (const float*)d_in[13];
  float* out = (float*)d_out;

  char* p = (char*)d_ws;
  u16* vid_bf   = (u16*)p;  p += 8192ull*2048*2;
  u16* txt_bf   = (u16*)p;  p += 256ull*2048*2;
  u16* Wqkv_v_t = (u16*)p;  p += 6144ull*2048*2;
  u16* Wqkv_t_t = (u16*)p;  p += 6144ull*2048*2;
  u16* Wo_v_t   = (u16*)p;  p += 2048ull*2048*2;
  u16* Wo_t_t   = (u16*)p;  p += 2048ull*2048*2;
  u16* vq_w     = (u16*)p;  p += 32ull*16*256*128*2;
  u16* vk_w     = (u16*)p;  p += 32ull*16*256*128*2;
  u16* vv_w     = (u16*)p;  p += 32ull*16*256*128*2;   // [win][head][key][d]
  u16* tq_w     = (u16*)p;  p += 16ull*256*128*2;
  u16* tk_w     = (u16*)p;  p += 16ull*256*128*2;
  u16* tv_w     = (u16*)p;  p += 16ull*256*128*2;      // [head][key][d]
  u16* vo_pre   = (u16*)p;  p += 8192ull*2048*2;
  float* to_pre = (float*)p; p += 256ull*2048*4;       // (unused)
  u16* to_bf    = (u16*)p;  p += 256ull*2048*2;
  // vvT/tvT alias vid_bf (dead after QKV gemms); tvT contiguous after vvT
  u16* vvT = vid_bf;                                    // [512 nh][128 d][256 key]
  // to_part aliases Wqkv_v_t (dead after QKV gemms): 32x256x2048 bf16 = 33.6 MB
  u16* to_part = Wqkv_v_t;
  (void)to_pre;

  // converts (merged)
  conv_all<<<dim3(16896), dim3(256), 0, stream>>>(vid, vid_bf, txt, txt_bf);
  tconv_all<<<dim3(32768), dim3(32,8), 0, stream>>>(Wqkv_v, Wqkv_v_t, Wqkv_t, Wqkv_t_t,
                                                    Wo_v, Wo_v_t, Wo_t, Wo_t_t);

  // QKV projections
  gemm256<0><<<dim3(24,32), dim3(512), 0, stream>>>(vid_bf, Wqkv_v_t, bqkv_v,
      vq_w, vk_w, vv_w, nullptr, 0, 8192, NQKV, DIM);
  gemm128p<1><<<dim3(48,2), dim3(256), 0, stream>>>(txt_bf, Wqkv_t_t, bqkv_t,
      tq_w, tk_w, tv_w, nullptr, 0, 256, NQKV, DIM);

  // V transpose (merged; vvT aliases vid_bf which is now dead)
  vtrans_all<<<dim3(528,4), dim3(256), 0, stream>>>(vv_w, tv_w, vvT);

  // K RMSNorm (merged; Q fused into attention)
  rms_all<<<dim3(33793), dim3(256), 0, stream>>>(vk_w, gk_v, tk_w, gk_t);

  // attention (2048 blocks, XCD-chunked; text rows -> per-window bf16 partials)
  attn_kernel<<<dim3(2048), dim3(512), 0, stream>>>(vq_w, vk_w, vvT, tq_w, tk_w,
                                                    vvT + 512ull*128*256,
                                                    gq_v, gq_t, vo_pre, to_part);

  // reduce text partials over windows -> to_bf
  reduce_txt<<<dim3(256), dim3(256), 0, stream>>>(to_part, to_bf);

  // output projections
  gemm256<2><<<dim3(8,32), dim3(512), 0, stream>>>(vo_pre, Wo_v_t, bo_v,
      nullptr, nullptr, nullptr, out, 2048, 8192, 2048, 2048);
  gemm128p<2><<<dim3(16,2), dim3(256), 0, stream>>>(to_bf, Wo_t_t, bo_t,
      nullptr, nullptr, nullptr, out + 16777216, 2048, 256, 2048, 2048);
}